// Round 3
// baseline (857.037 us; speedup 1.0000x reference)
//
#include <hip/hip_runtime.h>
#include <cmath>

#define H 96
#define W 96
#define HW 9216
#define CIN 256
#define COUT 256
#define NB 4
#define NCH 72   // K-chunks of 32 kc:  9 taps * 8 c-chunks
#define NPT 576  // 16-pixel tiles per image (9216/16)

typedef float f32x4 __attribute__((ext_vector_type(4)));
typedef short bf16x8 __attribute__((ext_vector_type(8)));

__device__ __forceinline__ unsigned short f2bf(float f) {
  unsigned int u = __float_as_uint(f);
  u += 0x7fff + ((u >> 16) & 1);  // round-to-nearest-even
  return (unsigned short)(u >> 16);
}

// ---------------------------------------------------------------------------
// Kernel 1: offset conv, channel-split 4-way. Block = 256 pixels, 64 channels,
// all 27 k (so x is read once per (block,c), not once per k-group).
// Writes raw partial sums P[cq][n][k][hw].
// ---------------------------------------------------------------------------
__global__ __launch_bounds__(256)
void offset_conv3(const float* __restrict__ x,
                  const float* __restrict__ w_off,
                  float* __restrict__ P) {
  int tid = threadIdx.x;
  int hw = blockIdx.x * 256 + tid;
  int cq = blockIdx.y;
  int n  = blockIdx.z;
  int h = hw / W, wv = hw % W;

  int   idx9[9];
  float m9[9];
#pragma unroll
  for (int ty = 0; ty < 3; ++ty) {
#pragma unroll
    for (int tx = 0; tx < 3; ++tx) {
      int iy = h + ty - 1, ix = wv + tx - 1;
      bool valid = (iy >= 0) && (iy < H) && (ix >= 0) && (ix < W);
      int iyc = min(max(iy, 0), H - 1), ixc = min(max(ix, 0), W - 1);
      idx9[ty * 3 + tx] = iyc * W + ixc;
      m9[ty * 3 + tx] = valid ? 1.f : 0.f;
    }
  }

  float acc[27];
#pragma unroll
  for (int kk = 0; kk < 27; ++kk) acc[kk] = 0.f;

  const float* xn = x + (size_t)n * CIN * HW;
  for (int cl = 0; cl < 64; ++cl) {
    int c = cq * 64 + cl;
    const float* xc = xn + (size_t)c * HW;
    float xv[9];
#pragma unroll
    for (int j = 0; j < 9; ++j) xv[j] = xc[idx9[j]] * m9[j];
#pragma unroll
    for (int kk = 0; kk < 27; ++kk) {
      const float* wr = w_off + (size_t)(kk * CIN + c) * 9;  // wave-uniform -> s_load
#pragma unroll
      for (int j = 0; j < 9; ++j) acc[kk] = fmaf(xv[j], wr[j], acc[kk]);
    }
  }

#pragma unroll
  for (int kk = 0; kk < 27; ++kk)
    P[((size_t)(cq * NB + n) * 27 + kk) * HW + hw] = acc[kk];
}

// ---------------------------------------------------------------------------
// Kernel 2: sum 4 channel-partials + bias -> py / px / sigmoid(mask)
// ---------------------------------------------------------------------------
__global__ __launch_bounds__(256)
void offset_finalize(const float* __restrict__ P,
                     const float* __restrict__ b_off,
                     float* __restrict__ py, float* __restrict__ px,
                     float* __restrict__ mk) {
  int gid = blockIdx.x * 256 + threadIdx.x;   // < NB*27*HW
  int hw = gid % HW;
  int kk = (gid / HW) % 27;
  int n  = gid / (27 * HW);
  float s = b_off[kk];
#pragma unroll
  for (int cq = 0; cq < 4; ++cq)
    s += P[((size_t)(cq * NB + n) * 27 + kk) * HW + hw];
  int h = hw / W, wv = hw % W;
  if (kk < 9) {
    py[(size_t)(n * 9 + kk) * HW + hw] = s + (float)h + (float)(kk / 3 - 1);
  } else if (kk < 18) {
    int j = kk - 9;
    px[(size_t)(n * 9 + j) * HW + hw] = s + (float)wv + (float)(j % 3 - 1);
  } else {
    mk[(size_t)(n * 9 + (kk - 18)) * HW + hw] = 1.f / (1.f + expf(-s));
  }
}

// ---------------------------------------------------------------------------
// Kernel 3: weights -> MFMA-A fragment order.
// Ag[ch][oTile(16)][lane(64)][8 bf16]: lane l of o-tile ot holds
// W[o = ot*16 + (l&15)][kc = ch-chunk base + (l>>4)*8 + j], kc = k*256+c,
// ch = k*8 + cc, c = cc*32 + (l>>4)*8 + j.
// ---------------------------------------------------------------------------
__global__ __launch_bounds__(256)
void wa_convert(const float* __restrict__ w, unsigned short* __restrict__ Ag) {
  int gid = blockIdx.x * 256 + threadIdx.x;  // < 72*16*64 = 73728
  int ch = gid >> 10;
  int rest = gid & 1023;
  int ot = rest >> 6, l = rest & 63;
  int o = ot * 16 + (l & 15);
  int k = ch >> 3, cc = ch & 7;
  int cbase = cc * 32 + (l >> 4) * 8;
  unsigned short r[8];
#pragma unroll
  for (int j = 0; j < 8; ++j)
    r[j] = f2bf(w[((size_t)o * CIN + cbase + j) * 9 + k]);
  uint4 pk;
  pk.x = (unsigned int)r[0] | ((unsigned int)r[1] << 16);
  pk.y = (unsigned int)r[2] | ((unsigned int)r[3] << 16);
  pk.z = (unsigned int)r[4] | ((unsigned int)r[5] << 16);
  pk.w = (unsigned int)r[6] | ((unsigned int)r[7] << 16);
  *(uint4*)(Ag + (size_t)gid * 8) = pk;
}

// ---------------------------------------------------------------------------
// Kernel 4: bilinear sampler -> S in MFMA-B fragment order.
// Block = 64 pixels (4 tiles), 256 thr = (pix, j=c-octet). Loop cc outer,
// tap k inner: the 9 taps' 2x2 neighborhoods overlap -> L1/L2 hot.
// S[n][ch][pixTile][lane][8 bf16]: lane l holds
// sample(pix = tile*16 + (l&15), c = cc*32 + (l>>4)*8 + j) * mask.
// ---------------------------------------------------------------------------
__global__ __launch_bounds__(256)
void sampler(const float* __restrict__ x,
             const float* __restrict__ py,
             const float* __restrict__ px,
             const float* __restrict__ mk,
             unsigned short* __restrict__ S) {
  __shared__ int   sIdx[9][4][64];
  __shared__ float sWgt[9][4][64];

  int tid = threadIdx.x;
  int pixBase = blockIdx.x * 64;
  int ptBase  = blockIdx.x * 4;
  int n       = blockIdx.y;

  if (tid < 64) {
    for (int k = 0; k < 9; ++k) {
      int off = (n * 9 + k) * HW + pixBase + tid;
      float fy = py[off], fx = px[off], fm = mk[off];
      float y0f = floorf(fy), x0f = floorf(fx);
      float ly = fy - y0f, lx = fx - x0f;
      int y0 = (int)y0f, x0 = (int)x0f;
      int cy0 = min(max(y0, 0), H - 1), cy1 = min(max(y0 + 1, 0), H - 1);
      int cx0 = min(max(x0, 0), W - 1), cx1 = min(max(x0 + 1, 0), W - 1);
      float vy0 = (y0 >= 0 && y0 <= H - 1) ? 1.f : 0.f;
      float vy1 = (y0 + 1 >= 0 && y0 + 1 <= H - 1) ? 1.f : 0.f;
      float vx0 = (x0 >= 0 && x0 <= W - 1) ? 1.f : 0.f;
      float vx1 = (x0 + 1 >= 0 && x0 + 1 <= W - 1) ? 1.f : 0.f;
      sIdx[k][0][tid] = cy0 * W + cx0;
      sIdx[k][1][tid] = cy0 * W + cx1;
      sIdx[k][2][tid] = cy1 * W + cx0;
      sIdx[k][3][tid] = cy1 * W + cx1;
      sWgt[k][0][tid] = (1.f - ly) * (1.f - lx) * fm * vy0 * vx0;
      sWgt[k][1][tid] = (1.f - ly) * lx * fm * vy0 * vx1;
      sWgt[k][2][tid] = ly * (1.f - lx) * fm * vy1 * vx0;
      sWgt[k][3][tid] = ly * lx * fm * vy1 * vx1;
    }
  }
  __syncthreads();

  int pix = tid & 63;
  int j   = tid >> 6;          // c-octet within 32-chunk (== MFMA kq)
  int pt  = ptBase + (pix >> 4);
  const float* xn = x + (size_t)n * CIN * HW;

  for (int cc = 0; cc < 8; ++cc) {
    for (int k = 0; k < 9; ++k) {
      int   i0 = sIdx[k][0][pix], i1 = sIdx[k][1][pix];
      int   i2 = sIdx[k][2][pix], i3 = sIdx[k][3][pix];
      float w0 = sWgt[k][0][pix], w1 = sWgt[k][1][pix];
      float w2 = sWgt[k][2][pix], w3 = sWgt[k][3][pix];
      unsigned short r[8];
#pragma unroll
      for (int jj = 0; jj < 8; ++jj) {
        const float* xc = xn + (size_t)(cc * 32 + j * 8 + jj) * HW;
        float v = xc[i0] * w0;
        v = fmaf(xc[i1], w1, v);
        v = fmaf(xc[i2], w2, v);
        v = fmaf(xc[i3], w3, v);
        r[jj] = f2bf(v);
      }
      uint4 pk;
      pk.x = (unsigned int)r[0] | ((unsigned int)r[1] << 16);
      pk.y = (unsigned int)r[2] | ((unsigned int)r[3] << 16);
      pk.z = (unsigned int)r[4] | ((unsigned int)r[5] << 16);
      pk.w = (unsigned int)r[6] | ((unsigned int)r[7] << 16);
      int ch = k * 8 + cc;
      size_t si = (((size_t)(n * NCH + ch)) * NPT + pt) * 512 + (size_t)((pix & 15) + j * 16) * 8;
      *(uint4*)(S + si) = pk;
    }
  }
}

// ---------------------------------------------------------------------------
// Kernel 5: streaming bf16 MFMA GEMM. Block = 8 waves = 256 couts x 64 pix.
// K-loop: 72 chunks of 32. B: LDS ping-pong (prefetch overlaps MFMA);
// A-frags straight from L2 in lane order. All ds_reads sequential ->
// conflict-free. Epilogue: pre-BN y + atomic per-channel sum/sumsq.
// ---------------------------------------------------------------------------
__global__ __launch_bounds__(512)
void gemm_mfma(const unsigned short* __restrict__ S,
               const unsigned short* __restrict__ Ag,
               float* __restrict__ out,
               float* __restrict__ sumArr, float* __restrict__ sqArr) {
  __shared__ unsigned short sB[2][2048];  // 2 x (4 tiles x 64 lanes x 8 bf16)

  int tid = threadIdx.x;
  int wv = tid >> 6, lane = tid & 63, quad = lane >> 4, l16 = lane & 15;
  int ptBase  = blockIdx.x * 4;
  int pixBase = blockIdx.x * 64;
  int n = blockIdx.y;

  f32x4 acc[2][4];
#pragma unroll
  for (int i = 0; i < 2; ++i)
#pragma unroll
    for (int pt = 0; pt < 4; ++pt) acc[i][pt] = (f32x4){0.f, 0.f, 0.f, 0.f};

  // prologue: chunk 0
  uint2 breg = *(const uint2*)(S + ((size_t)(n * NCH + 0) * NPT + ptBase) * 512 + tid * 4);
  bf16x8 afr[2];
#pragma unroll
  for (int ot = 0; ot < 2; ++ot)
    afr[ot] = *(const bf16x8*)(Ag + ((size_t)(0 * 16 + 2 * wv + ot) * 64 + lane) * 8);
  *(uint2*)(&sB[0][tid * 4]) = breg;
  __syncthreads();

  for (int ch = 0; ch < NCH; ++ch) {
    int p = ch & 1;
    uint2 bregn;
    bf16x8 afrn[2];
    if (ch < NCH - 1) {
      bregn = *(const uint2*)(S + ((size_t)(n * NCH + ch + 1) * NPT + ptBase) * 512 + tid * 4);
#pragma unroll
      for (int ot = 0; ot < 2; ++ot)
        afrn[ot] = *(const bf16x8*)(Ag + ((size_t)((ch + 1) * 16 + 2 * wv + ot) * 64 + lane) * 8);
    }

    bf16x8 bfr[4];
#pragma unroll
    for (int pt = 0; pt < 4; ++pt)
      bfr[pt] = *(const bf16x8*)(&sB[p][pt * 512 + lane * 8]);
#pragma unroll
    for (int pt = 0; pt < 4; ++pt) {
      acc[0][pt] = __builtin_amdgcn_mfma_f32_16x16x32_bf16(afr[0], bfr[pt], acc[0][pt], 0, 0, 0);
      acc[1][pt] = __builtin_amdgcn_mfma_f32_16x16x32_bf16(afr[1], bfr[pt], acc[1][pt], 0, 0, 0);
    }

    if (ch < NCH - 1) {
      __syncthreads();
      *(uint2*)(&sB[1 - p][tid * 4]) = bregn;
      __syncthreads();
      afr[0] = afrn[0];
      afr[1] = afrn[1];
    }
  }

  // Epilogue: D layout col = l16 (pix), row = quad*4 + r (o within 16-tile)
#pragma unroll
  for (int ot = 0; ot < 2; ++ot) {
#pragma unroll
    for (int r = 0; r < 4; ++r) {
      int o = (2 * wv + ot) * 16 + quad * 4 + r;
      float* rowp = out + (size_t)(n * COUT + o) * HW + pixBase;
      float s = 0.f, q = 0.f;
#pragma unroll
      for (int pt = 0; pt < 4; ++pt) {
        float v = acc[ot][pt][r];
        rowp[pt * 16 + l16] = v;
        s += v;
        q = fmaf(v, v, q);
      }
#pragma unroll
      for (int m = 8; m >= 1; m >>= 1) {
        s += __shfl_xor(s, m, 64);
        q += __shfl_xor(q, m, 64);
      }
      if (l16 == 0) {
        atomicAdd(&sumArr[o], s);
        atomicAdd(&sqArr[o], q);
      }
    }
  }
}

// ---------------------------------------------------------------------------
// Kernel 6: BN finalize -> per-channel scale/shift
// ---------------------------------------------------------------------------
__global__ __launch_bounds__(256)
void bn_finalize(const float* __restrict__ sumArr, const float* __restrict__ sqArr,
                 const float* __restrict__ gamma, const float* __restrict__ beta,
                 float* __restrict__ scaleArr, float* __restrict__ shiftArr) {
  int o = threadIdx.x;
  const float inv = 1.f / (float)(NB * HW);
  float mean = sumArr[o] * inv;
  float var = sqArr[o] * inv - mean * mean;
  float sc = rsqrtf(var + 1e-5f) * gamma[o];
  scaleArr[o] = sc;
  shiftArr[o] = beta[o] - mean * sc;
}

// ---------------------------------------------------------------------------
// Kernel 7: BN apply + ReLU, in-place, float4
// ---------------------------------------------------------------------------
__global__ __launch_bounds__(256)
void bn_apply(float* __restrict__ y,
              const float* __restrict__ scaleArr,
              const float* __restrict__ shiftArr) {
  int gid = blockIdx.x * 256 + threadIdx.x;
  int o = ((gid * 4) / HW) % COUT;
  float scale = scaleArr[o], shift = shiftArr[o];
  float4 v = ((float4*)y)[gid];
  v.x = fmaxf(fmaf(v.x, scale, shift), 0.f);
  v.y = fmaxf(fmaf(v.y, scale, shift), 0.f);
  v.z = fmaxf(fmaf(v.z, scale, shift), 0.f);
  v.w = fmaxf(fmaf(v.w, scale, shift), 0.f);
  ((float4*)y)[gid] = v;
}

// ---------------------------------------------------------------------------
extern "C" void kernel_launch(void* const* d_in, const int* in_sizes, int n_in,
                              void* d_out, int out_size, void* d_ws, size_t ws_size,
                              hipStream_t stream) {
  const float* x     = (const float*)d_in[0];
  const float* w_off = (const float*)d_in[1];
  const float* b_off = (const float*)d_in[2];
  const float* w     = (const float*)d_in[3];
  // d_in[4] = b : cancels exactly in BN mean-subtraction
  const float* gamma = (const float*)d_in[5];
  const float* beta  = (const float*)d_in[6];
  float* out = (float*)d_out;

  float* ws = (float*)d_ws;
  float* py = ws;                          // 331776
  float* px = py + 331776;                 // 331776
  float* mk = px + 331776;                 // 331776
  float* P  = mk + 331776;                 // 4*4*27*9216 = 3981312
  unsigned short* Ag = (unsigned short*)(P + 3981312);  // 589824 u16
  float* sumArr   = (float*)(Ag + 589824); // 256
  float* sqArr    = sumArr + 256;
  float* scaleArr = sqArr + 256;
  float* shiftArr = scaleArr + 256;
  unsigned short* S = (unsigned short*)(shiftArr + 256);  // 4*72*576*512 u16 = 170 MB

  hipMemsetAsync(sumArr, 0, 512 * sizeof(float), stream);

  dim3 gOff(HW / 256, 4, NB);
  offset_conv3<<<gOff, 256, 0, stream>>>(x, w_off, P);
  offset_finalize<<<(NB * 27 * HW) / 256, 256, 0, stream>>>(P, b_off, py, px, mk);
  wa_convert<<<(NCH * 16 * 64) / 256, 256, 0, stream>>>(w, Ag);

  dim3 gS(HW / 64, NB);
  sampler<<<gS, 256, 0, stream>>>(x, py, px, mk, S);

  dim3 gG(HW / 64, NB);
  gemm_mfma<<<gG, 512, 0, stream>>>(S, Ag, out, sumArr, sqArr);

  bn_finalize<<<1, 256, 0, stream>>>(sumArr, sqArr, gamma, beta, scaleArr, shiftArr);
  bn_apply<<<(NB * COUT * HW / 4) / 256, 256, 0, stream>>>(out, scaleArr, shiftArr);
}

// Round 4
// 566.752 us; speedup vs baseline: 1.5122x; 1.5122x over previous
//
#include <hip/hip_runtime.h>
#include <cmath>

#define H 96
#define W 96
#define HW 9216
#define CIN 256
#define COUT 256
#define NB 4
#define NCH 72   // K-chunks of 32 kc:  9 taps * 8 c-chunks
#define NPT 576  // 16-pixel tiles per image (9216/16)

typedef float f32x4 __attribute__((ext_vector_type(4)));
typedef short bf16x8 __attribute__((ext_vector_type(8)));

__device__ __forceinline__ unsigned short f2bf(float f) {
  unsigned int u = __float_as_uint(f);
  u += 0x7fff + ((u >> 16) & 1);  // round-to-nearest-even
  return (unsigned short)(u >> 16);
}

// ---------------------------------------------------------------------------
// Kernel W1: main weights -> MFMA-A fragment order.
// Ag[ch][oTile(16)][lane(64)][8 bf16]: o = ot*16+(l&15), c = cc*32+(l>>4)*8+j,
// k = ch>>3, cc = ch&7.
// ---------------------------------------------------------------------------
__global__ __launch_bounds__(256)
void wa_convert(const float* __restrict__ w, unsigned short* __restrict__ Ag) {
  int gid = blockIdx.x * 256 + threadIdx.x;  // < 72*16*64 = 73728
  int ch = gid >> 10;
  int rest = gid & 1023;
  int ot = rest >> 6, l = rest & 63;
  int o = ot * 16 + (l & 15);
  int k = ch >> 3, cc = ch & 7;
  int cbase = cc * 32 + (l >> 4) * 8;
  unsigned short r[8];
#pragma unroll
  for (int j = 0; j < 8; ++j)
    r[j] = f2bf(w[((size_t)o * CIN + cbase + j) * 9 + k]);
  uint4 pk;
  pk.x = (unsigned int)r[0] | ((unsigned int)r[1] << 16);
  pk.y = (unsigned int)r[2] | ((unsigned int)r[3] << 16);
  pk.z = (unsigned int)r[4] | ((unsigned int)r[5] << 16);
  pk.w = (unsigned int)r[6] | ((unsigned int)r[7] << 16);
  *(uint4*)(Ag + (size_t)gid * 8) = pk;
}

// ---------------------------------------------------------------------------
// Kernel W2: offset weights (27,Cin,3,3) -> A-frag order, padded to 32 rows.
// Ag2[ch][ot(2)][lane(64)][8 bf16], o = ot*16+(l&15) (zero for o>=27).
// ---------------------------------------------------------------------------
__global__ __launch_bounds__(256)
void wa2_convert(const float* __restrict__ w_off, unsigned short* __restrict__ Ag2) {
  int gid = blockIdx.x * 256 + threadIdx.x;  // < 72*2*64 = 9216
  int ch = gid >> 7;
  int rest = gid & 127;
  int ot = rest >> 6, l = rest & 63;
  int o = ot * 16 + (l & 15);
  int k = ch >> 3, cc = ch & 7;
  int cbase = cc * 32 + (l >> 4) * 8;
  unsigned short r[8];
#pragma unroll
  for (int j = 0; j < 8; ++j)
    r[j] = (o < 27) ? f2bf(w_off[((size_t)o * CIN + cbase + j) * 9 + k]) : (unsigned short)0;
  uint4 pk;
  pk.x = (unsigned int)r[0] | ((unsigned int)r[1] << 16);
  pk.y = (unsigned int)r[2] | ((unsigned int)r[3] << 16);
  pk.z = (unsigned int)r[4] | ((unsigned int)r[5] << 16);
  pk.w = (unsigned int)r[6] | ((unsigned int)r[7] << 16);
  *(uint4*)(Ag2 + (size_t)gid * 8) = pk;
}

// ---------------------------------------------------------------------------
// Kernel O: offset conv as bf16 MFMA GEMM. M=32 (27 used), K=2304, N=36864.
// Block = 512 thr (8 waves) x 128 pixels; wave wv owns pixel-tile wv,
// o-tiles {0,1}. B staged from x with integer (clamped) taps, LDS ping-pong
// + register prefetch. Epilogue: +bias, +coords / sigmoid -> py/px/mk.
// ---------------------------------------------------------------------------
__global__ __launch_bounds__(512)
void offset_gemm(const float* __restrict__ x,
                 const unsigned short* __restrict__ Ag2,
                 const float* __restrict__ b_off,
                 float* __restrict__ py, float* __restrict__ px,
                 float* __restrict__ mk) {
  __shared__ unsigned short sB[2][4096];  // 8 tiles x 64 lanes x 8 bf16

  int tid = threadIdx.x;
  int wv = tid >> 6, lane = tid & 63, quad = lane >> 4, l16 = lane & 15;
  int pixBase = blockIdx.x * 128;
  int n = blockIdx.y;

  // staging role: q = c-octet, pl = pixel in block
  int q = tid >> 7;
  int pl = tid & 127;
  int tile = pl >> 4, lp = pl & 15;
  int laneStore = q * 16 + lp;
  int hwp = pixBase + pl;
  int hh = hwp / W, wx = hwp % W;
  const float* xn = x + (size_t)n * CIN * HW;

  f32x4 acc[2];
  acc[0] = (f32x4){0.f, 0.f, 0.f, 0.f};
  acc[1] = (f32x4){0.f, 0.f, 0.f, 0.f};

  // ---- stage chunk into regs ----
  auto stage = [&](int ch, uint4& pk, bf16x8* afr) {
    int k = ch >> 3, cc = ch & 7;
    int iy = hh + k / 3 - 1, ix = wx + k % 3 - 1;
    bool valid = (iy >= 0) && (iy < H) && (ix >= 0) && (ix < W);
    int pos = min(max(iy, 0), H - 1) * W + min(max(ix, 0), W - 1);
    float m = valid ? 1.f : 0.f;
    const float* xb = xn + (size_t)(cc * 32 + q * 8) * HW + pos;
    unsigned short r[8];
#pragma unroll
    for (int jj = 0; jj < 8; ++jj) r[jj] = f2bf(xb[(size_t)jj * HW] * m);
    pk.x = (unsigned int)r[0] | ((unsigned int)r[1] << 16);
    pk.y = (unsigned int)r[2] | ((unsigned int)r[3] << 16);
    pk.z = (unsigned int)r[4] | ((unsigned int)r[5] << 16);
    pk.w = (unsigned int)r[6] | ((unsigned int)r[7] << 16);
    afr[0] = *(const bf16x8*)(Ag2 + ((size_t)(ch * 2 + 0) * 64 + lane) * 8);
    afr[1] = *(const bf16x8*)(Ag2 + ((size_t)(ch * 2 + 1) * 64 + lane) * 8);
  };

  uint4 pk;
  bf16x8 afr[2], afrn[2];
  stage(0, pk, afr);
  *(uint4*)(&sB[0][(size_t)tile * 512 + laneStore * 8]) = pk;
  __syncthreads();

  for (int ch = 0; ch < NCH; ++ch) {
    int p = ch & 1;
    uint4 pkn;
    if (ch < NCH - 1) stage(ch + 1, pkn, afrn);

    bf16x8 bfr = *(const bf16x8*)(&sB[p][(size_t)wv * 512 + lane * 8]);
    acc[0] = __builtin_amdgcn_mfma_f32_16x16x32_bf16(afr[0], bfr, acc[0], 0, 0, 0);
    acc[1] = __builtin_amdgcn_mfma_f32_16x16x32_bf16(afr[1], bfr, acc[1], 0, 0, 0);

    if (ch < NCH - 1) {
      __syncthreads();
      *(uint4*)(&sB[1 - p][(size_t)tile * 512 + laneStore * 8]) = pkn;
      __syncthreads();
      afr[0] = afrn[0];
      afr[1] = afrn[1];
    }
  }

  // Epilogue: D col = l16 (pix), row = quad*4+r (o). Wave's pixels:
  int pix = pixBase + wv * 16 + l16;
  int he = pix / W, we = pix % W;
#pragma unroll
  for (int ot = 0; ot < 2; ++ot) {
#pragma unroll
    for (int r = 0; r < 4; ++r) {
      int kk = ot * 16 + quad * 4 + r;
      if (kk >= 27) continue;
      float v = acc[ot][r] + b_off[kk];
      if (kk < 9) {
        py[(size_t)(n * 9 + kk) * HW + pix] = v + (float)he + (float)(kk / 3 - 1);
      } else if (kk < 18) {
        int j = kk - 9;
        px[(size_t)(n * 9 + j) * HW + pix] = v + (float)we + (float)(j % 3 - 1);
      } else {
        mk[(size_t)(n * 9 + (kk - 18)) * HW + pix] = 1.f / (1.f + expf(-v));
      }
    }
  }
}

// ---------------------------------------------------------------------------
// Kernel S: bilinear sampler -> S in MFMA-B fragment order.
// Block = 64 pixels, 256 thr = (pix, j=c-octet). Loop cc outer, tap k inner.
// S[n][ch][pixTile][lane][8 bf16].
// ---------------------------------------------------------------------------
__global__ __launch_bounds__(256)
void sampler(const float* __restrict__ x,
             const float* __restrict__ py,
             const float* __restrict__ px,
             const float* __restrict__ mk,
             unsigned short* __restrict__ S) {
  __shared__ int   sIdx[9][4][64];
  __shared__ float sWgt[9][4][64];

  int tid = threadIdx.x;
  int pixBase = blockIdx.x * 64;
  int ptBase  = blockIdx.x * 4;
  int n       = blockIdx.y;

  if (tid < 64) {
    for (int k = 0; k < 9; ++k) {
      int off = (n * 9 + k) * HW + pixBase + tid;
      float fy = py[off], fx = px[off], fm = mk[off];
      float y0f = floorf(fy), x0f = floorf(fx);
      float ly = fy - y0f, lx = fx - x0f;
      int y0 = (int)y0f, x0 = (int)x0f;
      int cy0 = min(max(y0, 0), H - 1), cy1 = min(max(y0 + 1, 0), H - 1);
      int cx0 = min(max(x0, 0), W - 1), cx1 = min(max(x0 + 1, 0), W - 1);
      float vy0 = (y0 >= 0 && y0 <= H - 1) ? 1.f : 0.f;
      float vy1 = (y0 + 1 >= 0 && y0 + 1 <= H - 1) ? 1.f : 0.f;
      float vx0 = (x0 >= 0 && x0 <= W - 1) ? 1.f : 0.f;
      float vx1 = (x0 + 1 >= 0 && x0 + 1 <= W - 1) ? 1.f : 0.f;
      sIdx[k][0][tid] = cy0 * W + cx0;
      sIdx[k][1][tid] = cy0 * W + cx1;
      sIdx[k][2][tid] = cy1 * W + cx0;
      sIdx[k][3][tid] = cy1 * W + cx1;
      sWgt[k][0][tid] = (1.f - ly) * (1.f - lx) * fm * vy0 * vx0;
      sWgt[k][1][tid] = (1.f - ly) * lx * fm * vy0 * vx1;
      sWgt[k][2][tid] = ly * (1.f - lx) * fm * vy1 * vx0;
      sWgt[k][3][tid] = ly * lx * fm * vy1 * vx1;
    }
  }
  __syncthreads();

  int pix = tid & 63;
  int j   = tid >> 6;          // c-octet within 32-chunk (== MFMA kq)
  int pt  = ptBase + (pix >> 4);
  const float* xn = x + (size_t)n * CIN * HW;

  for (int cc = 0; cc < 8; ++cc) {
    for (int k = 0; k < 9; ++k) {
      int   i0 = sIdx[k][0][pix], i1 = sIdx[k][1][pix];
      int   i2 = sIdx[k][2][pix], i3 = sIdx[k][3][pix];
      float w0 = sWgt[k][0][pix], w1 = sWgt[k][1][pix];
      float w2 = sWgt[k][2][pix], w3 = sWgt[k][3][pix];
      unsigned short r[8];
#pragma unroll
      for (int jj = 0; jj < 8; ++jj) {
        const float* xc = xn + (size_t)(cc * 32 + j * 8 + jj) * HW;
        float v = xc[i0] * w0;
        v = fmaf(xc[i1], w1, v);
        v = fmaf(xc[i2], w2, v);
        v = fmaf(xc[i3], w3, v);
        r[jj] = f2bf(v);
      }
      uint4 pk;
      pk.x = (unsigned int)r[0] | ((unsigned int)r[1] << 16);
      pk.y = (unsigned int)r[2] | ((unsigned int)r[3] << 16);
      pk.z = (unsigned int)r[4] | ((unsigned int)r[5] << 16);
      pk.w = (unsigned int)r[6] | ((unsigned int)r[7] << 16);
      int ch = k * 8 + cc;
      size_t si = (((size_t)(n * NCH + ch)) * NPT + pt) * 512 + (size_t)((pix & 15) + j * 16) * 8;
      *(uint4*)(S + si) = pk;
    }
  }
}

// ---------------------------------------------------------------------------
// Kernel G: streaming bf16 MFMA GEMM. Block = 8 waves = 256 couts x 128 pix.
// K-loop: 72 chunks of 32. B: LDS ping-pong + register prefetch; A straight
// from L2 in lane order. Epilogue: pre-BN y + atomic per-channel sum/sumsq.
// ---------------------------------------------------------------------------
__global__ __launch_bounds__(512)
void gemm_mfma(const unsigned short* __restrict__ S,
               const unsigned short* __restrict__ Ag,
               float* __restrict__ out,
               float* __restrict__ sumArr, float* __restrict__ sqArr) {
  __shared__ unsigned short sB[2][4096];  // 8 tiles x 64 lanes x 8 bf16

  int tid = threadIdx.x;
  int wv = tid >> 6, lane = tid & 63, quad = lane >> 4, l16 = lane & 15;
  int ptBase  = blockIdx.x * 8;
  int pixBase = blockIdx.x * 128;
  int n = blockIdx.y;

  f32x4 acc[2][8];
#pragma unroll
  for (int i = 0; i < 2; ++i)
#pragma unroll
    for (int pt = 0; pt < 8; ++pt) acc[i][pt] = (f32x4){0.f, 0.f, 0.f, 0.f};

  // prologue: chunk 0
  uint4 breg = *(const uint4*)(S + ((size_t)(n * NCH + 0) * NPT + ptBase) * 512 + tid * 8);
  bf16x8 afr[2];
#pragma unroll
  for (int ot = 0; ot < 2; ++ot)
    afr[ot] = *(const bf16x8*)(Ag + ((size_t)(0 * 16 + 2 * wv + ot) * 64 + lane) * 8);
  *(uint4*)(&sB[0][tid * 8]) = breg;
  __syncthreads();

  for (int ch = 0; ch < NCH; ++ch) {
    int p = ch & 1;
    uint4 bregn;
    bf16x8 afrn[2];
    if (ch < NCH - 1) {
      bregn = *(const uint4*)(S + ((size_t)(n * NCH + ch + 1) * NPT + ptBase) * 512 + tid * 8);
#pragma unroll
      for (int ot = 0; ot < 2; ++ot)
        afrn[ot] = *(const bf16x8*)(Ag + ((size_t)((ch + 1) * 16 + 2 * wv + ot) * 64 + lane) * 8);
    }

#pragma unroll
    for (int pt = 0; pt < 8; ++pt) {
      bf16x8 bfr = *(const bf16x8*)(&sB[p][pt * 512 + lane * 8]);
      acc[0][pt] = __builtin_amdgcn_mfma_f32_16x16x32_bf16(afr[0], bfr, acc[0][pt], 0, 0, 0);
      acc[1][pt] = __builtin_amdgcn_mfma_f32_16x16x32_bf16(afr[1], bfr, acc[1][pt], 0, 0, 0);
    }

    if (ch < NCH - 1) {
      __syncthreads();
      *(uint4*)(&sB[1 - p][tid * 8]) = bregn;
      __syncthreads();
      afr[0] = afrn[0];
      afr[1] = afrn[1];
    }
  }

  // Epilogue: D col = l16 (pix), row = quad*4 + r (o within 16-tile)
#pragma unroll
  for (int ot = 0; ot < 2; ++ot) {
#pragma unroll
    for (int r = 0; r < 4; ++r) {
      int o = (2 * wv + ot) * 16 + quad * 4 + r;
      float* rowp = out + (size_t)(n * COUT + o) * HW + pixBase;
      float s = 0.f, q = 0.f;
#pragma unroll
      for (int pt = 0; pt < 8; ++pt) {
        float v = acc[ot][pt][r];
        rowp[pt * 16 + l16] = v;
        s += v;
        q = fmaf(v, v, q);
      }
#pragma unroll
      for (int m = 8; m >= 1; m >>= 1) {
        s += __shfl_xor(s, m, 64);
        q += __shfl_xor(q, m, 64);
      }
      if (l16 == 0) {
        atomicAdd(&sumArr[o], s);
        atomicAdd(&sqArr[o], q);
      }
    }
  }
}

// ---------------------------------------------------------------------------
// BN finalize + apply
// ---------------------------------------------------------------------------
__global__ __launch_bounds__(256)
void bn_finalize(const float* __restrict__ sumArr, const float* __restrict__ sqArr,
                 const float* __restrict__ gamma, const float* __restrict__ beta,
                 float* __restrict__ scaleArr, float* __restrict__ shiftArr) {
  int o = threadIdx.x;
  const float inv = 1.f / (float)(NB * HW);
  float mean = sumArr[o] * inv;
  float var = sqArr[o] * inv - mean * mean;
  float sc = rsqrtf(var + 1e-5f) * gamma[o];
  scaleArr[o] = sc;
  shiftArr[o] = beta[o] - mean * sc;
}

__global__ __launch_bounds__(256)
void bn_apply(float* __restrict__ y,
              const float* __restrict__ scaleArr,
              const float* __restrict__ shiftArr) {
  int gid = blockIdx.x * 256 + threadIdx.x;
  int o = ((gid * 4) / HW) % COUT;
  float scale = scaleArr[o], shift = shiftArr[o];
  float4 v = ((float4*)y)[gid];
  v.x = fmaxf(fmaf(v.x, scale, shift), 0.f);
  v.y = fmaxf(fmaf(v.y, scale, shift), 0.f);
  v.z = fmaxf(fmaf(v.z, scale, shift), 0.f);
  v.w = fmaxf(fmaf(v.w, scale, shift), 0.f);
  ((float4*)y)[gid] = v;
}

// ---------------------------------------------------------------------------
extern "C" void kernel_launch(void* const* d_in, const int* in_sizes, int n_in,
                              void* d_out, int out_size, void* d_ws, size_t ws_size,
                              hipStream_t stream) {
  const float* x     = (const float*)d_in[0];
  const float* w_off = (const float*)d_in[1];
  const float* b_off = (const float*)d_in[2];
  const float* w     = (const float*)d_in[3];
  // d_in[4] = b : cancels exactly in BN mean-subtraction
  const float* gamma = (const float*)d_in[5];
  const float* beta  = (const float*)d_in[6];
  float* out = (float*)d_out;

  float* ws = (float*)d_ws;
  float* py = ws;                          // 331776 f
  float* px = py + 331776;
  float* mk = px + 331776;
  unsigned short* Ag  = (unsigned short*)(mk + 331776);  // 589824 u16
  unsigned short* Ag2 = Ag + 589824;                     // 73728 u16
  float* sumArr   = (float*)(Ag2 + 73728);
  float* sqArr    = sumArr + 256;
  float* scaleArr = sqArr + 256;
  float* shiftArr = scaleArr + 256;
  unsigned short* S = (unsigned short*)(shiftArr + 256);  // 4*72*576*512 u16 = 170 MB

  hipMemsetAsync(sumArr, 0, 512 * sizeof(float), stream);

  wa_convert<<<(NCH * 16 * 64) / 256, 256, 0, stream>>>(w, Ag);
  wa2_convert<<<(NCH * 2 * 64) / 256, 256, 0, stream>>>(w_off, Ag2);

  dim3 gO(HW / 128, NB);
  offset_gemm<<<gO, 512, 0, stream>>>(x, Ag2, b_off, py, px, mk);

  dim3 gS(HW / 64, NB);
  sampler<<<gS, 256, 0, stream>>>(x, py, px, mk, S);

  dim3 gG(HW / 128, NB);
  gemm_mfma<<<gG, 512, 0, stream>>>(S, Ag, out, sumArr, sqArr);

  bn_finalize<<<1, 256, 0, stream>>>(sumArr, sqArr, gamma, beta, scaleArr, shiftArr);
  bn_apply<<<(NB * COUT * HW / 4) / 256, 256, 0, stream>>>(out, scaleArr, shiftArr);
}

// Round 5
// 503.572 us; speedup vs baseline: 1.7019x; 1.1255x over previous
//
#include <hip/hip_runtime.h>
#include <cmath>

#define H 96
#define W 96
#define HW 9216
#define CIN 256
#define COUT 256
#define NB 4
#define NCH 72   // K-chunks of 32 kc:  9 taps * 8 c-chunks
#define NPT 576  // 16-pixel tiles per image (9216/16)

typedef float f32x4 __attribute__((ext_vector_type(4)));
typedef short bf16x8 __attribute__((ext_vector_type(8)));

__device__ __forceinline__ unsigned short f2bf(float f) {
  unsigned int u = __float_as_uint(f);
  u += 0x7fff + ((u >> 16) & 1);  // round-to-nearest-even
  return (unsigned short)(u >> 16);
}
__device__ __forceinline__ float bf2f(unsigned short u) {
  return __uint_as_float(((unsigned int)u) << 16);
}

// ---------------------------------------------------------------------------
// Kernel W1: main weights -> MFMA-A fragment order.
// Ag[ch][oTile(16)][lane(64)][8 bf16]: o = ot*16+(l&15), c = cc*32+(l>>4)*8+j
// ---------------------------------------------------------------------------
__global__ __launch_bounds__(256)
void wa_convert(const float* __restrict__ w, unsigned short* __restrict__ Ag) {
  int gid = blockIdx.x * 256 + threadIdx.x;  // < 72*16*64 = 73728
  int ch = gid >> 10;
  int rest = gid & 1023;
  int ot = rest >> 6, l = rest & 63;
  int o = ot * 16 + (l & 15);
  int k = ch >> 3, cc = ch & 7;
  int cbase = cc * 32 + (l >> 4) * 8;
  unsigned short r[8];
#pragma unroll
  for (int j = 0; j < 8; ++j)
    r[j] = f2bf(w[((size_t)o * CIN + cbase + j) * 9 + k]);
  uint4 pk;
  pk.x = (unsigned int)r[0] | ((unsigned int)r[1] << 16);
  pk.y = (unsigned int)r[2] | ((unsigned int)r[3] << 16);
  pk.z = (unsigned int)r[4] | ((unsigned int)r[5] << 16);
  pk.w = (unsigned int)r[6] | ((unsigned int)r[7] << 16);
  *(uint4*)(Ag + (size_t)gid * 8) = pk;
}

// ---------------------------------------------------------------------------
// Kernel W2: offset weights -> A-frag order, padded to 32 rows.
// ---------------------------------------------------------------------------
__global__ __launch_bounds__(256)
void wa2_convert(const float* __restrict__ w_off, unsigned short* __restrict__ Ag2) {
  int gid = blockIdx.x * 256 + threadIdx.x;  // < 72*2*64 = 9216
  int ch = gid >> 7;
  int rest = gid & 127;
  int ot = rest >> 6, l = rest & 63;
  int o = ot * 16 + (l & 15);
  int k = ch >> 3, cc = ch & 7;
  int cbase = cc * 32 + (l >> 4) * 8;
  unsigned short r[8];
#pragma unroll
  for (int j = 0; j < 8; ++j)
    r[j] = (o < 27) ? f2bf(w_off[((size_t)o * CIN + cbase + j) * 9 + k]) : (unsigned short)0;
  uint4 pk;
  pk.x = (unsigned int)r[0] | ((unsigned int)r[1] << 16);
  pk.y = (unsigned int)r[2] | ((unsigned int)r[3] << 16);
  pk.z = (unsigned int)r[4] | ((unsigned int)r[5] << 16);
  pk.w = (unsigned int)r[6] | ((unsigned int)r[7] << 16);
  *(uint4*)(Ag2 + (size_t)gid * 8) = pk;
}

// ---------------------------------------------------------------------------
// Kernel O: offset conv as bf16 MFMA GEMM. M=32 (27 used), K=2304.
// Block = 256 thr (4 waves) x 64 pixels; wave wv = pixel-tile wv, both
// o-tiles. B staged from x (integer taps), LDS ping-pong + reg prefetch.
// grid (144,4) = 576 blocks -> 2.25 blocks/CU.
// ---------------------------------------------------------------------------
__global__ __launch_bounds__(256)
void offset_gemm(const float* __restrict__ x,
                 const unsigned short* __restrict__ Ag2,
                 const float* __restrict__ b_off,
                 float* __restrict__ py, float* __restrict__ px,
                 float* __restrict__ mk) {
  __shared__ unsigned short sB[2][2048];  // 4 tiles x 64 lanes x 8 bf16

  int tid = threadIdx.x;
  int wv = tid >> 6, lane = tid & 63, quad = lane >> 4, l16 = lane & 15;
  int pixBase = blockIdx.x * 64;
  int n = blockIdx.y;

  // staging role: q = c-octet, pl = pixel in block
  int q = tid >> 6;
  int pl = tid & 63;
  int tile = pl >> 4, lp = pl & 15;
  int laneStore = q * 16 + lp;
  int hwp = pixBase + pl;
  int hh = hwp / W, wx = hwp % W;
  const float* xn = x + (size_t)n * CIN * HW;

  f32x4 acc[2];
  acc[0] = (f32x4){0.f, 0.f, 0.f, 0.f};
  acc[1] = (f32x4){0.f, 0.f, 0.f, 0.f};

  auto stage = [&](int ch, uint4& pk, bf16x8* afr) {
    int k = ch >> 3, cc = ch & 7;
    int iy = hh + k / 3 - 1, ix = wx + k % 3 - 1;
    bool valid = (iy >= 0) && (iy < H) && (ix >= 0) && (ix < W);
    int pos = min(max(iy, 0), H - 1) * W + min(max(ix, 0), W - 1);
    float m = valid ? 1.f : 0.f;
    const float* xb = xn + (size_t)(cc * 32 + q * 8) * HW + pos;
    unsigned short r[8];
#pragma unroll
    for (int jj = 0; jj < 8; ++jj) r[jj] = f2bf(xb[(size_t)jj * HW] * m);
    pk.x = (unsigned int)r[0] | ((unsigned int)r[1] << 16);
    pk.y = (unsigned int)r[2] | ((unsigned int)r[3] << 16);
    pk.z = (unsigned int)r[4] | ((unsigned int)r[5] << 16);
    pk.w = (unsigned int)r[6] | ((unsigned int)r[7] << 16);
    afr[0] = *(const bf16x8*)(Ag2 + ((size_t)(ch * 2 + 0) * 64 + lane) * 8);
    afr[1] = *(const bf16x8*)(Ag2 + ((size_t)(ch * 2 + 1) * 64 + lane) * 8);
  };

  uint4 pk;
  bf16x8 afr[2], afrn[2];
  stage(0, pk, afr);
  *(uint4*)(&sB[0][(size_t)tile * 512 + laneStore * 8]) = pk;
  __syncthreads();

  for (int ch = 0; ch < NCH; ++ch) {
    int p = ch & 1;
    uint4 pkn;
    if (ch < NCH - 1) stage(ch + 1, pkn, afrn);

    bf16x8 bfr = *(const bf16x8*)(&sB[p][(size_t)wv * 512 + lane * 8]);
    acc[0] = __builtin_amdgcn_mfma_f32_16x16x32_bf16(afr[0], bfr, acc[0], 0, 0, 0);
    acc[1] = __builtin_amdgcn_mfma_f32_16x16x32_bf16(afr[1], bfr, acc[1], 0, 0, 0);

    if (ch < NCH - 1) {
      __syncthreads();
      *(uint4*)(&sB[1 - p][(size_t)tile * 512 + laneStore * 8]) = pkn;
      __syncthreads();
      afr[0] = afrn[0];
      afr[1] = afrn[1];
    }
  }

  // Epilogue: D col = l16 (pix), row = quad*4+r (kk)
  int pix = pixBase + wv * 16 + l16;
  int he = pix / W, we = pix % W;
#pragma unroll
  for (int ot = 0; ot < 2; ++ot) {
#pragma unroll
    for (int r = 0; r < 4; ++r) {
      int kk = ot * 16 + quad * 4 + r;
      if (kk >= 27) continue;
      float v = acc[ot][r] + b_off[kk];
      if (kk < 9) {
        py[(size_t)(n * 9 + kk) * HW + pix] = v + (float)he + (float)(kk / 3 - 1);
      } else if (kk < 18) {
        int j = kk - 9;
        px[(size_t)(n * 9 + j) * HW + pix] = v + (float)we + (float)(j % 3 - 1);
      } else {
        mk[(size_t)(n * 9 + (kk - 18)) * HW + pix] = 1.f / (1.f + expf(-v));
      }
    }
  }
}

// ---------------------------------------------------------------------------
// Kernel S: bilinear sampler -> S in MFMA-B fragment order.
// Grid (144 pixel-blocks, 8 cc-chunks, NB): 4608 blocks for latency hiding.
// Block = 64 pixels x one 32-channel chunk; 256 thr = (pix, j=c-octet).
// ---------------------------------------------------------------------------
__global__ __launch_bounds__(256)
void sampler(const float* __restrict__ x,
             const float* __restrict__ py,
             const float* __restrict__ px,
             const float* __restrict__ mk,
             unsigned short* __restrict__ S) {
  __shared__ int   sIdx[9][4][64];
  __shared__ float sWgt[9][4][64];

  int tid = threadIdx.x;
  int pixBase = blockIdx.x * 64;
  int ptBase  = blockIdx.x * 4;
  int cc      = blockIdx.y;
  int n       = blockIdx.z;

  {
    int pix0 = tid & 63;
    for (int k = tid >> 6; k < 9; k += 4) {
      int off = (n * 9 + k) * HW + pixBase + pix0;
      float fy = py[off], fx = px[off], fm = mk[off];
      float y0f = floorf(fy), x0f = floorf(fx);
      float ly = fy - y0f, lx = fx - x0f;
      int y0 = (int)y0f, x0 = (int)x0f;
      int cy0 = min(max(y0, 0), H - 1), cy1 = min(max(y0 + 1, 0), H - 1);
      int cx0 = min(max(x0, 0), W - 1), cx1 = min(max(x0 + 1, 0), W - 1);
      float vy0 = (y0 >= 0 && y0 <= H - 1) ? 1.f : 0.f;
      float vy1 = (y0 + 1 >= 0 && y0 + 1 <= H - 1) ? 1.f : 0.f;
      float vx0 = (x0 >= 0 && x0 <= W - 1) ? 1.f : 0.f;
      float vx1 = (x0 + 1 >= 0 && x0 + 1 <= W - 1) ? 1.f : 0.f;
      sIdx[k][0][pix0] = cy0 * W + cx0;
      sIdx[k][1][pix0] = cy0 * W + cx1;
      sIdx[k][2][pix0] = cy1 * W + cx0;
      sIdx[k][3][pix0] = cy1 * W + cx1;
      sWgt[k][0][pix0] = (1.f - ly) * (1.f - lx) * fm * vy0 * vx0;
      sWgt[k][1][pix0] = (1.f - ly) * lx * fm * vy0 * vx1;
      sWgt[k][2][pix0] = ly * (1.f - lx) * fm * vy1 * vx0;
      sWgt[k][3][pix0] = ly * lx * fm * vy1 * vx1;
    }
  }
  __syncthreads();

  int pix = tid & 63;
  int j   = tid >> 6;          // c-octet within 32-chunk (== MFMA quad)
  int pt  = ptBase + (pix >> 4);
  const float* xn = x + (size_t)n * CIN * HW;

  for (int k = 0; k < 9; ++k) {
    int   i0 = sIdx[k][0][pix], i1 = sIdx[k][1][pix];
    int   i2 = sIdx[k][2][pix], i3 = sIdx[k][3][pix];
    float w0 = sWgt[k][0][pix], w1 = sWgt[k][1][pix];
    float w2 = sWgt[k][2][pix], w3 = sWgt[k][3][pix];
    unsigned short r[8];
#pragma unroll
    for (int jj = 0; jj < 8; ++jj) {
      const float* xc = xn + (size_t)(cc * 32 + j * 8 + jj) * HW;
      float v = xc[i0] * w0;
      v = fmaf(xc[i1], w1, v);
      v = fmaf(xc[i2], w2, v);
      v = fmaf(xc[i3], w3, v);
      r[jj] = f2bf(v);
    }
    uint4 pk;
    pk.x = (unsigned int)r[0] | ((unsigned int)r[1] << 16);
    pk.y = (unsigned int)r[2] | ((unsigned int)r[3] << 16);
    pk.z = (unsigned int)r[4] | ((unsigned int)r[5] << 16);
    pk.w = (unsigned int)r[6] | ((unsigned int)r[7] << 16);
    int ch = k * 8 + cc;
    size_t si = (((size_t)(n * NCH + ch)) * NPT + pt) * 512 + (size_t)((pix & 15) + j * 16) * 8;
    *(uint4*)(S + si) = pk;
  }
}

// ---------------------------------------------------------------------------
// Kernel G: streaming bf16 MFMA GEMM. Block = 8 waves = 256 couts x 64 pix.
// grid (144,4) = 576 blocks. B: LDS ping-pong + reg prefetch; A from L2.
// Output: pre-BN y as bf16 + atomic per-channel sum/sumsq (fp32 from acc).
// ---------------------------------------------------------------------------
__global__ __launch_bounds__(512)
void gemm_mfma(const unsigned short* __restrict__ S,
               const unsigned short* __restrict__ Ag,
               unsigned short* __restrict__ yb,
               float* __restrict__ sumArr, float* __restrict__ sqArr) {
  __shared__ unsigned short sB[2][2048];  // 4 tiles x 64 lanes x 8 bf16

  int tid = threadIdx.x;
  int wv = tid >> 6, lane = tid & 63, quad = lane >> 4, l16 = lane & 15;
  int ptBase  = blockIdx.x * 4;
  int pixBase = blockIdx.x * 64;
  int n = blockIdx.y;

  f32x4 acc[2][4];
#pragma unroll
  for (int i = 0; i < 2; ++i)
#pragma unroll
    for (int pt = 0; pt < 4; ++pt) acc[i][pt] = (f32x4){0.f, 0.f, 0.f, 0.f};

  // prologue: chunk 0
  uint2 breg = *(const uint2*)(S + ((size_t)(n * NCH + 0) * NPT + ptBase) * 512 + tid * 4);
  bf16x8 afr[2];
#pragma unroll
  for (int ot = 0; ot < 2; ++ot)
    afr[ot] = *(const bf16x8*)(Ag + ((size_t)(0 * 16 + 2 * wv + ot) * 64 + lane) * 8);
  *(uint2*)(&sB[0][tid * 4]) = breg;
  __syncthreads();

  for (int ch = 0; ch < NCH; ++ch) {
    int p = ch & 1;
    uint2 bregn;
    bf16x8 afrn[2];
    if (ch < NCH - 1) {
      bregn = *(const uint2*)(S + ((size_t)(n * NCH + ch + 1) * NPT + ptBase) * 512 + tid * 4);
#pragma unroll
      for (int ot = 0; ot < 2; ++ot)
        afrn[ot] = *(const bf16x8*)(Ag + ((size_t)((ch + 1) * 16 + 2 * wv + ot) * 64 + lane) * 8);
    }

#pragma unroll
    for (int pt = 0; pt < 4; ++pt) {
      bf16x8 bfr = *(const bf16x8*)(&sB[p][pt * 512 + lane * 8]);
      acc[0][pt] = __builtin_amdgcn_mfma_f32_16x16x32_bf16(afr[0], bfr, acc[0][pt], 0, 0, 0);
      acc[1][pt] = __builtin_amdgcn_mfma_f32_16x16x32_bf16(afr[1], bfr, acc[1][pt], 0, 0, 0);
    }

    if (ch < NCH - 1) {
      __syncthreads();
      *(uint2*)(&sB[1 - p][tid * 4]) = bregn;
      __syncthreads();
      afr[0] = afrn[0];
      afr[1] = afrn[1];
    }
  }

  // Epilogue: D col = l16 (pix), row = quad*4 + r (o within 16-tile)
#pragma unroll
  for (int ot = 0; ot < 2; ++ot) {
#pragma unroll
    for (int r = 0; r < 4; ++r) {
      int o = (2 * wv + ot) * 16 + quad * 4 + r;
      unsigned short* rowp = yb + (size_t)(n * COUT + o) * HW + pixBase;
      float s = 0.f, q = 0.f;
#pragma unroll
      for (int pt = 0; pt < 4; ++pt) {
        float v = acc[ot][pt][r];
        rowp[pt * 16 + l16] = f2bf(v);
        s += v;
        q = fmaf(v, v, q);
      }
#pragma unroll
      for (int m = 8; m >= 1; m >>= 1) {
        s += __shfl_xor(s, m, 64);
        q += __shfl_xor(q, m, 64);
      }
      if (l16 == 0) {
        atomicAdd(&sumArr[o], s);
        atomicAdd(&sqArr[o], q);
      }
    }
  }
}

// ---------------------------------------------------------------------------
// BN finalize + apply (bf16 y -> fp32 out)
// ---------------------------------------------------------------------------
__global__ __launch_bounds__(256)
void bn_finalize(const float* __restrict__ sumArr, const float* __restrict__ sqArr,
                 const float* __restrict__ gamma, const float* __restrict__ beta,
                 float* __restrict__ scaleArr, float* __restrict__ shiftArr) {
  int o = threadIdx.x;
  const float inv = 1.f / (float)(NB * HW);
  float mean = sumArr[o] * inv;
  float var = sqArr[o] * inv - mean * mean;
  float sc = rsqrtf(var + 1e-5f) * gamma[o];
  scaleArr[o] = sc;
  shiftArr[o] = beta[o] - mean * sc;
}

__global__ __launch_bounds__(256)
void bn_apply(const unsigned short* __restrict__ yb,
              float* __restrict__ out,
              const float* __restrict__ scaleArr,
              const float* __restrict__ shiftArr) {
  int gid = blockIdx.x * 256 + threadIdx.x;  // < NB*COUT*HW/8
  int base = gid * 8;
  int o = (base / HW) % COUT;
  float scale = scaleArr[o], shift = shiftArr[o];
  uint4 v = ((const uint4*)yb)[gid];
  float4 a, b;
  a.x = fmaxf(fmaf(bf2f((unsigned short)(v.x & 0xffff)), scale, shift), 0.f);
  a.y = fmaxf(fmaf(bf2f((unsigned short)(v.x >> 16)), scale, shift), 0.f);
  a.z = fmaxf(fmaf(bf2f((unsigned short)(v.y & 0xffff)), scale, shift), 0.f);
  a.w = fmaxf(fmaf(bf2f((unsigned short)(v.y >> 16)), scale, shift), 0.f);
  b.x = fmaxf(fmaf(bf2f((unsigned short)(v.z & 0xffff)), scale, shift), 0.f);
  b.y = fmaxf(fmaf(bf2f((unsigned short)(v.z >> 16)), scale, shift), 0.f);
  b.z = fmaxf(fmaf(bf2f((unsigned short)(v.w & 0xffff)), scale, shift), 0.f);
  b.w = fmaxf(fmaf(bf2f((unsigned short)(v.w >> 16)), scale, shift), 0.f);
  *(float4*)&out[base] = a;
  *(float4*)&out[base + 4] = b;
}

// ---------------------------------------------------------------------------
extern "C" void kernel_launch(void* const* d_in, const int* in_sizes, int n_in,
                              void* d_out, int out_size, void* d_ws, size_t ws_size,
                              hipStream_t stream) {
  const float* x     = (const float*)d_in[0];
  const float* w_off = (const float*)d_in[1];
  const float* b_off = (const float*)d_in[2];
  const float* w     = (const float*)d_in[3];
  // d_in[4] = b : cancels exactly in BN mean-subtraction
  const float* gamma = (const float*)d_in[5];
  const float* beta  = (const float*)d_in[6];
  float* out = (float*)d_out;

  float* ws = (float*)d_ws;
  float* py = ws;                          // 331776 f
  float* px = py + 331776;
  float* mk = px + 331776;
  unsigned short* Ag  = (unsigned short*)(mk + 331776);  // 589824 u16
  unsigned short* Ag2 = Ag + 589824;                     // 73728 u16
  float* sumArr   = (float*)(Ag2 + 73728);
  float* sqArr    = sumArr + 256;
  float* scaleArr = sqArr + 256;
  float* shiftArr = scaleArr + 256;
  unsigned short* yb = (unsigned short*)(shiftArr + 256);  // 9437184 u16
  unsigned short* S  = yb + 9437184;       // 84934656 u16 = 170 MB

  hipMemsetAsync(sumArr, 0, 512 * sizeof(float), stream);

  wa_convert<<<(NCH * 16 * 64) / 256, 256, 0, stream>>>(w, Ag);
  wa2_convert<<<(NCH * 2 * 64) / 256, 256, 0, stream>>>(w_off, Ag2);

  dim3 gO(HW / 64, NB);
  offset_gemm<<<gO, 256, 0, stream>>>(x, Ag2, b_off, py, px, mk);

  dim3 gS(HW / 64, 8, NB);
  sampler<<<gS, 256, 0, stream>>>(x, py, px, mk, S);

  dim3 gG(HW / 64, NB);
  gemm_mfma<<<gG, 512, 0, stream>>>(S, Ag, yb, sumArr, sqArr);

  bn_finalize<<<1, 256, 0, stream>>>(sumArr, sqArr, gamma, beta, scaleArr, shiftArr);
  bn_apply<<<(NB * COUT * HW / 8) / 256, 256, 0, stream>>>(yb, out, scaleArr, shiftArr);
}

// Round 6
// 406.749 us; speedup vs baseline: 2.1070x; 1.2380x over previous
//
#include <hip/hip_runtime.h>
#include <cmath>

#define H 96
#define W 96
#define HW 9216
#define CIN 256
#define COUT 256
#define NB 4
#define NCH 72   // K-chunks of 32 kc: 9 taps * 8 c-chunks

typedef float f32x4 __attribute__((ext_vector_type(4)));
typedef short bf16x8 __attribute__((ext_vector_type(8)));

__device__ __forceinline__ unsigned short f2bf(float f) {
  unsigned int u = __float_as_uint(f);
  u += 0x7fff + ((u >> 16) & 1);  // round-to-nearest-even
  return (unsigned short)(u >> 16);
}
__device__ __forceinline__ float bf2f(unsigned short u) {
  return __uint_as_float(((unsigned int)u) << 16);
}

// ---------------------------------------------------------------------------
// Kernel T: x (N,C,HW) fp32 -> xT (N,HW,C) bf16 via LDS tile.
// Block: 64 c x 64 hw. Reads coalesced float4, writes coalesced 32 B runs.
// ---------------------------------------------------------------------------
__global__ __launch_bounds__(256)
void xt_convert(const float* __restrict__ x, unsigned short* __restrict__ xT) {
  __shared__ unsigned short ls[64][72];  // [hw][c], pitch 72 (rows 16B-aligned)
  int tid = threadIdx.x;
  int hwbase = blockIdx.x * 64;
  int cbase  = blockIdx.y * 64;
  int n      = blockIdx.z;

  {
    int cl = tid >> 2, qd = tid & 3;
    const float* src = x + ((size_t)(n * CIN + cbase + cl)) * HW + hwbase + qd * 16;
#pragma unroll
    for (int m = 0; m < 4; ++m) {
      float4 v = *(const float4*)(src + m * 4);
      int hwl = qd * 16 + m * 4;
      ls[hwl + 0][cl] = f2bf(v.x);
      ls[hwl + 1][cl] = f2bf(v.y);
      ls[hwl + 2][cl] = f2bf(v.z);
      ls[hwl + 3][cl] = f2bf(v.w);
    }
  }
  __syncthreads();
  {
    int hw = tid >> 2, part = tid & 3;
    unsigned short* dst = xT + ((size_t)(n * HW + hwbase + hw)) * CIN + cbase + part * 16;
    *(uint4*)(dst + 0) = *(const uint4*)(&ls[hw][part * 16 + 0]);
    *(uint4*)(dst + 8) = *(const uint4*)(&ls[hw][part * 16 + 8]);
  }
}

// ---------------------------------------------------------------------------
// Kernel W1: main weights -> MFMA-A fragment order.
// Ag[ch][oTile(16)][lane(64)][8 bf16]: o = ot*16+(l&15), c = cc*32+(l>>4)*8+j
// ---------------------------------------------------------------------------
__global__ __launch_bounds__(256)
void wa_convert(const float* __restrict__ w, unsigned short* __restrict__ Ag) {
  int gid = blockIdx.x * 256 + threadIdx.x;  // < 72*16*64 = 73728
  int ch = gid >> 10;
  int rest = gid & 1023;
  int ot = rest >> 6, l = rest & 63;
  int o = ot * 16 + (l & 15);
  int k = ch >> 3, cc = ch & 7;
  int cbase = cc * 32 + (l >> 4) * 8;
  unsigned short r[8];
#pragma unroll
  for (int j = 0; j < 8; ++j)
    r[j] = f2bf(w[((size_t)o * CIN + cbase + j) * 9 + k]);
  uint4 pk;
  pk.x = (unsigned int)r[0] | ((unsigned int)r[1] << 16);
  pk.y = (unsigned int)r[2] | ((unsigned int)r[3] << 16);
  pk.z = (unsigned int)r[4] | ((unsigned int)r[5] << 16);
  pk.w = (unsigned int)r[6] | ((unsigned int)r[7] << 16);
  *(uint4*)(Ag + (size_t)gid * 8) = pk;
}

// ---------------------------------------------------------------------------
// Kernel W2: offset weights -> A-frag order, padded to 32 rows.
// ---------------------------------------------------------------------------
__global__ __launch_bounds__(256)
void wa2_convert(const float* __restrict__ w_off, unsigned short* __restrict__ Ag2) {
  int gid = blockIdx.x * 256 + threadIdx.x;  // < 72*2*64 = 9216
  int ch = gid >> 7;
  int rest = gid & 127;
  int ot = rest >> 6, l = rest & 63;
  int o = ot * 16 + (l & 15);
  int k = ch >> 3, cc = ch & 7;
  int cbase = cc * 32 + (l >> 4) * 8;
  unsigned short r[8];
#pragma unroll
  for (int j = 0; j < 8; ++j)
    r[j] = (o < 27) ? f2bf(w_off[((size_t)o * CIN + cbase + j) * 9 + k]) : (unsigned short)0;
  uint4 pk;
  pk.x = (unsigned int)r[0] | ((unsigned int)r[1] << 16);
  pk.y = (unsigned int)r[2] | ((unsigned int)r[3] << 16);
  pk.z = (unsigned int)r[4] | ((unsigned int)r[5] << 16);
  pk.w = (unsigned int)r[6] | ((unsigned int)r[7] << 16);
  *(uint4*)(Ag2 + (size_t)gid * 8) = pk;
}

// ---------------------------------------------------------------------------
// Kernel O: offset conv as bf16 MFMA GEMM over xT. M=32 (27 used), K=2304.
// Block = 256 thr (4 waves) x 64 pixels. B-staging: one 16-B xT load per
// thread per chunk (integer taps, zeroed when OOB). Single barrier/chunk.
// ---------------------------------------------------------------------------
__global__ __launch_bounds__(256)
void offset_gemm(const unsigned short* __restrict__ xT,
                 const unsigned short* __restrict__ Ag2,
                 const float* __restrict__ b_off,
                 float* __restrict__ py, float* __restrict__ px,
                 float* __restrict__ mk) {
  __shared__ unsigned short sB[2][2048];  // 4 tiles x 64 lanes x 8 bf16

  int tid = threadIdx.x;
  int wv = tid >> 6, lane = tid & 63, quad = lane >> 4, l16 = lane & 15;
  int pixBase = blockIdx.x * 64;
  int n = blockIdx.y;

  // staging role: q = c-octet (0..3), pl = pixel in block
  int q = tid >> 6;
  int pl = tid & 63;
  int tile = pl >> 4, lp = pl & 15;
  int hwp = pixBase + pl;
  int hh = hwp / W, wx = hwp % W;
  const unsigned short* xTn = xT + (size_t)n * HW * CIN;

  // 9 integer tap positions for this thread's pixel
  int pos9[9];
  bool ok9[9];
#pragma unroll
  for (int ty = 0; ty < 3; ++ty) {
#pragma unroll
    for (int tx = 0; tx < 3; ++tx) {
      int iy = hh + ty - 1, ix = wx + tx - 1;
      ok9[ty * 3 + tx] = (iy >= 0) && (iy < H) && (ix >= 0) && (ix < W);
      pos9[ty * 3 + tx] = min(max(iy, 0), H - 1) * W + min(max(ix, 0), W - 1);
    }
  }

  f32x4 acc[2];
  acc[0] = (f32x4){0.f, 0.f, 0.f, 0.f};
  acc[1] = (f32x4){0.f, 0.f, 0.f, 0.f};

  auto stage = [&](int ch, uint4& pk, bf16x8* afr) {
    int k = ch >> 3, cc = ch & 7;
    pk = *(const uint4*)(xTn + (size_t)pos9[k] * CIN + cc * 32 + q * 8);
    if (!ok9[k]) pk = (uint4){0, 0, 0, 0};
    afr[0] = *(const bf16x8*)(Ag2 + ((size_t)(ch * 2 + 0) * 64 + lane) * 8);
    afr[1] = *(const bf16x8*)(Ag2 + ((size_t)(ch * 2 + 1) * 64 + lane) * 8);
  };

  uint4 pk;
  bf16x8 afr[2], afrn[2];
  stage(0, pk, afr);
  *(uint4*)(&sB[0][(size_t)tile * 512 + (q * 16 + lp) * 8]) = pk;
  __syncthreads();

  for (int ch = 0; ch < NCH; ++ch) {
    int p = ch & 1;
    uint4 pkn;
    if (ch < NCH - 1) stage(ch + 1, pkn, afrn);

    bf16x8 bfr = *(const bf16x8*)(&sB[p][(size_t)wv * 512 + lane * 8]);
    acc[0] = __builtin_amdgcn_mfma_f32_16x16x32_bf16(afr[0], bfr, acc[0], 0, 0, 0);
    acc[1] = __builtin_amdgcn_mfma_f32_16x16x32_bf16(afr[1], bfr, acc[1], 0, 0, 0);

    if (ch < NCH - 1) {
      *(uint4*)(&sB[1 - p][(size_t)tile * 512 + (q * 16 + lp) * 8]) = pkn;
      __syncthreads();
      afr[0] = afrn[0];
      afr[1] = afrn[1];
    }
  }

  // Epilogue: D col = l16 (pix), row = quad*4+r (kk)
  int pix = pixBase + wv * 16 + l16;
  int he = pix / W, we = pix % W;
#pragma unroll
  for (int ot = 0; ot < 2; ++ot) {
#pragma unroll
    for (int r = 0; r < 4; ++r) {
      int kk = ot * 16 + quad * 4 + r;
      if (kk >= 27) continue;
      float v = acc[ot][r] + b_off[kk];
      if (kk < 9) {
        py[(size_t)(n * 9 + kk) * HW + pix] = v + (float)he + (float)(kk / 3 - 1);
      } else if (kk < 18) {
        int j = kk - 9;
        px[(size_t)(n * 9 + j) * HW + pix] = v + (float)we + (float)(j % 3 - 1);
      } else {
        mk[(size_t)(n * 9 + (kk - 18)) * HW + pix] = 1.f / (1.f + expf(-v));
      }
    }
  }
}

// ---------------------------------------------------------------------------
// Kernel G: FUSED bilinear-sample + bf16 MFMA GEMM over xT.
// Block = 512 thr (8 waves) = 256 couts x 64 pixels; grid (144, NB).
// Prologue: 64 pix x 9 taps of corner indices/weights into LDS.
// Per chunk ch=(k,cc): each thread samples 4 channels (4 x 8-B corner loads,
// 16 FMA blend) -> sB ping-pong; 8 MFMA/wave; ONE barrier per chunk.
// Epilogue: yb bf16 + atomic per-channel sum/sumsq.
// ---------------------------------------------------------------------------
__global__ __launch_bounds__(512)
void fused_gemm(const unsigned short* __restrict__ xT,
                const unsigned short* __restrict__ Ag,
                const float* __restrict__ py,
                const float* __restrict__ px,
                const float* __restrict__ mk,
                unsigned short* __restrict__ yb,
                float* __restrict__ sumArr, float* __restrict__ sqArr) {
  __shared__ int   sIdx[9][4][64];
  __shared__ float sWgt[9][4][64];
  __shared__ unsigned short sB[2][2048];  // 4 tiles x 64 lanes x 8 bf16

  int tid = threadIdx.x;
  int wv = tid >> 6, lane = tid & 63, quad = lane >> 4, l16 = lane & 15;
  int pixBase = blockIdx.x * 64;
  int n = blockIdx.y;
  const unsigned short* xTn = xT + (size_t)n * HW * CIN;

  // ---- prologue: corner indices + mask-folded weights for 64 pix x 9 taps
  {
    int pix0 = tid & 63;
    int k0 = tid >> 6;
#pragma unroll
    for (int rep = 0; rep < 2; ++rep) {
      int k = (rep == 0) ? k0 : 8;
      if (rep == 1 && tid >= 64) break;
      int off = (n * 9 + k) * HW + pixBase + pix0;
      float fy = py[off], fx = px[off], fm = mk[off];
      float y0f = floorf(fy), x0f = floorf(fx);
      float ly = fy - y0f, lx = fx - x0f;
      int y0 = (int)y0f, x0 = (int)x0f;
      int cy0 = min(max(y0, 0), H - 1), cy1 = min(max(y0 + 1, 0), H - 1);
      int cx0 = min(max(x0, 0), W - 1), cx1 = min(max(x0 + 1, 0), W - 1);
      float vy0 = (y0 >= 0 && y0 <= H - 1) ? 1.f : 0.f;
      float vy1 = (y0 + 1 >= 0 && y0 + 1 <= H - 1) ? 1.f : 0.f;
      float vx0 = (x0 >= 0 && x0 <= W - 1) ? 1.f : 0.f;
      float vx1 = (x0 + 1 >= 0 && x0 + 1 <= W - 1) ? 1.f : 0.f;
      sIdx[k][0][pix0] = cy0 * W + cx0;
      sIdx[k][1][pix0] = cy0 * W + cx1;
      sIdx[k][2][pix0] = cy1 * W + cx0;
      sIdx[k][3][pix0] = cy1 * W + cx1;
      sWgt[k][0][pix0] = (1.f - ly) * (1.f - lx) * fm * vy0 * vx0;
      sWgt[k][1][pix0] = (1.f - ly) * lx * fm * vy0 * vx1;
      sWgt[k][2][pix0] = ly * (1.f - lx) * fm * vy1 * vx0;
      sWgt[k][3][pix0] = ly * lx * fm * vy1 * vx1;
    }
  }
  __syncthreads();

  // staging role: thread -> (pix = lane, oct = wv&3, half = wv>>2)
  int sPix = lane;
  int oct = wv & 3, half = wv >> 2;
  int sTile = sPix >> 4, sLp = sPix & 15;
  int cOff = oct * 8 + half * 4;                    // within 32-chunk
  int sAddr = sTile * 512 + (oct * 16 + sLp) * 8 + half * 4;

  f32x4 acc[2][4];
#pragma unroll
  for (int i = 0; i < 2; ++i)
#pragma unroll
    for (int pt = 0; pt < 4; ++pt) acc[i][pt] = (f32x4){0.f, 0.f, 0.f, 0.f};

  // issue corner loads + weight reads for chunk ch
  uint2 c0, c1, c2, c3;
  float w0, w1, w2, w3;
  auto sload = [&](int ch) {
    int k = ch >> 3, cc = ch & 7;
    int co = cc * 32 + cOff;
    c0 = *(const uint2*)(xTn + (size_t)sIdx[k][0][sPix] * CIN + co);
    c1 = *(const uint2*)(xTn + (size_t)sIdx[k][1][sPix] * CIN + co);
    c2 = *(const uint2*)(xTn + (size_t)sIdx[k][2][sPix] * CIN + co);
    c3 = *(const uint2*)(xTn + (size_t)sIdx[k][3][sPix] * CIN + co);
    w0 = sWgt[k][0][sPix]; w1 = sWgt[k][1][sPix];
    w2 = sWgt[k][2][sPix]; w3 = sWgt[k][3][sPix];
  };
  auto sblend = [&]() -> uint2 {
    unsigned short r[4];
#pragma unroll
    for (int jj = 0; jj < 4; ++jj) {
      unsigned int u0 = (jj < 2) ? c0.x : c0.y;
      unsigned int u1 = (jj < 2) ? c1.x : c1.y;
      unsigned int u2 = (jj < 2) ? c2.x : c2.y;
      unsigned int u3 = (jj < 2) ? c3.x : c3.y;
      int sh = (jj & 1) * 16;
      float v = bf2f((unsigned short)(u0 >> sh)) * w0;
      v = fmaf(bf2f((unsigned short)(u1 >> sh)), w1, v);
      v = fmaf(bf2f((unsigned short)(u2 >> sh)), w2, v);
      v = fmaf(bf2f((unsigned short)(u3 >> sh)), w3, v);
      r[jj] = f2bf(v);
    }
    uint2 pk;
    pk.x = (unsigned int)r[0] | ((unsigned int)r[1] << 16);
    pk.y = (unsigned int)r[2] | ((unsigned int)r[3] << 16);
    return pk;
  };

  // prologue: chunk 0 staged
  bf16x8 afr[2], afrn[2];
  sload(0);
  {
    uint2 pk = sblend();
    *(uint2*)(&sB[0][sAddr]) = pk;
  }
#pragma unroll
  for (int ot = 0; ot < 2; ++ot)
    afr[ot] = *(const bf16x8*)(Ag + ((size_t)(2 * wv + ot) * 64 + lane) * 8);
  __syncthreads();

  for (int ch = 0; ch < NCH; ++ch) {
    int p = ch & 1;
    if (ch < NCH - 1) {
      sload(ch + 1);  // issue early; consumed after MFMA
#pragma unroll
      for (int ot = 0; ot < 2; ++ot)
        afrn[ot] = *(const bf16x8*)(Ag + ((size_t)((ch + 1) * 16 + 2 * wv + ot) * 64 + lane) * 8);
    }

    bf16x8 bfr[4];
#pragma unroll
    for (int pt = 0; pt < 4; ++pt)
      bfr[pt] = *(const bf16x8*)(&sB[p][pt * 512 + lane * 8]);
#pragma unroll
    for (int pt = 0; pt < 4; ++pt) {
      acc[0][pt] = __builtin_amdgcn_mfma_f32_16x16x32_bf16(afr[0], bfr[pt], acc[0][pt], 0, 0, 0);
      acc[1][pt] = __builtin_amdgcn_mfma_f32_16x16x32_bf16(afr[1], bfr[pt], acc[1][pt], 0, 0, 0);
    }

    if (ch < NCH - 1) {
      uint2 pk = sblend();
      *(uint2*)(&sB[1 - p][sAddr]) = pk;
      __syncthreads();
      afr[0] = afrn[0];
      afr[1] = afrn[1];
    }
  }

  // Epilogue: D col = l16 (pix), row = quad*4 + r (o within 16-tile)
#pragma unroll
  for (int ot = 0; ot < 2; ++ot) {
#pragma unroll
    for (int r = 0; r < 4; ++r) {
      int o = (2 * wv + ot) * 16 + quad * 4 + r;
      unsigned short* rowp = yb + (size_t)(n * COUT + o) * HW + pixBase;
      float s = 0.f, q = 0.f;
#pragma unroll
      for (int pt = 0; pt < 4; ++pt) {
        float v = acc[ot][pt][r];
        rowp[pt * 16 + l16] = f2bf(v);
        s += v;
        q = fmaf(v, v, q);
      }
#pragma unroll
      for (int m = 8; m >= 1; m >>= 1) {
        s += __shfl_xor(s, m, 64);
        q += __shfl_xor(q, m, 64);
      }
      if (l16 == 0) {
        atomicAdd(&sumArr[o], s);
        atomicAdd(&sqArr[o], q);
      }
    }
  }
}

// ---------------------------------------------------------------------------
// BN finalize + apply (bf16 y -> fp32 out)
// ---------------------------------------------------------------------------
__global__ __launch_bounds__(256)
void bn_finalize(const float* __restrict__ sumArr, const float* __restrict__ sqArr,
                 const float* __restrict__ gamma, const float* __restrict__ beta,
                 float* __restrict__ scaleArr, float* __restrict__ shiftArr) {
  int o = threadIdx.x;
  const float inv = 1.f / (float)(NB * HW);
  float mean = sumArr[o] * inv;
  float var = sqArr[o] * inv - mean * mean;
  float sc = rsqrtf(var + 1e-5f) * gamma[o];
  scaleArr[o] = sc;
  shiftArr[o] = beta[o] - mean * sc;
}

__global__ __launch_bounds__(256)
void bn_apply(const unsigned short* __restrict__ yb,
              float* __restrict__ out,
              const float* __restrict__ scaleArr,
              const float* __restrict__ shiftArr) {
  int gid = blockIdx.x * 256 + threadIdx.x;  // < NB*COUT*HW/8
  int base = gid * 8;
  int o = (base / HW) % COUT;
  float scale = scaleArr[o], shift = shiftArr[o];
  uint4 v = ((const uint4*)yb)[gid];
  float4 a, b;
  a.x = fmaxf(fmaf(bf2f((unsigned short)(v.x & 0xffff)), scale, shift), 0.f);
  a.y = fmaxf(fmaf(bf2f((unsigned short)(v.x >> 16)), scale, shift), 0.f);
  a.z = fmaxf(fmaf(bf2f((unsigned short)(v.y & 0xffff)), scale, shift), 0.f);
  a.w = fmaxf(fmaf(bf2f((unsigned short)(v.y >> 16)), scale, shift), 0.f);
  b.x = fmaxf(fmaf(bf2f((unsigned short)(v.z & 0xffff)), scale, shift), 0.f);
  b.y = fmaxf(fmaf(bf2f((unsigned short)(v.z >> 16)), scale, shift), 0.f);
  b.z = fmaxf(fmaf(bf2f((unsigned short)(v.w & 0xffff)), scale, shift), 0.f);
  b.w = fmaxf(fmaf(bf2f((unsigned short)(v.w >> 16)), scale, shift), 0.f);
  *(float4*)&out[base] = a;
  *(float4*)&out[base + 4] = b;
}

// ---------------------------------------------------------------------------
extern "C" void kernel_launch(void* const* d_in, const int* in_sizes, int n_in,
                              void* d_out, int out_size, void* d_ws, size_t ws_size,
                              hipStream_t stream) {
  const float* x     = (const float*)d_in[0];
  const float* w_off = (const float*)d_in[1];
  const float* b_off = (const float*)d_in[2];
  const float* w     = (const float*)d_in[3];
  // d_in[4] = b : cancels exactly in BN mean-subtraction
  const float* gamma = (const float*)d_in[5];
  const float* beta  = (const float*)d_in[6];
  float* out = (float*)d_out;

  float* ws = (float*)d_ws;
  float* py = ws;                          // 331776 f
  float* px = py + 331776;
  float* mk = px + 331776;
  unsigned short* Ag  = (unsigned short*)(mk + 331776);  // 589824 u16
  unsigned short* Ag2 = Ag + 589824;                     // 73728 u16
  float* sumArr   = (float*)(Ag2 + 73728);
  float* sqArr    = sumArr + 256;
  float* scaleArr = sqArr + 256;
  float* shiftArr = scaleArr + 256;
  unsigned short* yb = (unsigned short*)(shiftArr + 256);  // 9437184 u16
  unsigned short* xT = yb + 9437184;                       // 9437184 u16

  hipMemsetAsync(sumArr, 0, 512 * sizeof(float), stream);

  dim3 gT(HW / 64, CIN / 64, NB);
  xt_convert<<<gT, 256, 0, stream>>>(x, xT);

  wa_convert<<<(NCH * 16 * 64) / 256, 256, 0, stream>>>(w, Ag);
  wa2_convert<<<(NCH * 2 * 64) / 256, 256, 0, stream>>>(w_off, Ag2);

  dim3 gO(HW / 64, NB);
  offset_gemm<<<gO, 256, 0, stream>>>(xT, Ag2, b_off, py, px, mk);

  dim3 gG(HW / 64, NB);
  fused_gemm<<<gG, 512, 0, stream>>>(xT, Ag, py, px, mk, yb, sumArr, sqArr);

  bn_finalize<<<1, 256, 0, stream>>>(sumArr, sqArr, gamma, beta, scaleArr, shiftArr);
  bn_apply<<<(NB * COUT * HW / 8) / 256, 256, 0, stream>>>(yb, out, scaleArr, shiftArr);
}

// Round 7
// 334.646 us; speedup vs baseline: 2.5610x; 1.2155x over previous
//
#include <hip/hip_runtime.h>
#include <cmath>

#define H 96
#define W 96
#define HW 9216
#define CIN 256
#define COUT 256
#define NB 4
#define NCH 72   // K-chunks of 32 kc
#define NGR 36   // K-groups of 64 kc (2 chunks): g = cc2*9 + k

typedef float f32x4 __attribute__((ext_vector_type(4)));
typedef short bf16x8 __attribute__((ext_vector_type(8)));

__device__ __forceinline__ unsigned short f2bf(float f) {
  unsigned int u = __float_as_uint(f);
  u += 0x7fff + ((u >> 16) & 1);  // round-to-nearest-even
  return (unsigned short)(u >> 16);
}
__device__ __forceinline__ float bf2f(unsigned short u) {
  return __uint_as_float(((unsigned int)u) << 16);
}
__device__ __forceinline__ float bfLo(unsigned int u) {
  return __uint_as_float(u << 16);
}
__device__ __forceinline__ float bfHi(unsigned int u) {
  return __uint_as_float(u & 0xffff0000u);
}

// ---------------------------------------------------------------------------
// Kernel T: x (N,C,HW) fp32 -> xT (N,HW,C) bf16 via LDS tile.
// ---------------------------------------------------------------------------
__global__ __launch_bounds__(256)
void xt_convert(const float* __restrict__ x, unsigned short* __restrict__ xT) {
  __shared__ unsigned short ls[64][72];
  int tid = threadIdx.x;
  int hwbase = blockIdx.x * 64;
  int cbase  = blockIdx.y * 64;
  int n      = blockIdx.z;

  {
    int cl = tid >> 2, qd = tid & 3;
    const float* src = x + ((size_t)(n * CIN + cbase + cl)) * HW + hwbase + qd * 16;
#pragma unroll
    for (int m = 0; m < 4; ++m) {
      float4 v = *(const float4*)(src + m * 4);
      int hwl = qd * 16 + m * 4;
      ls[hwl + 0][cl] = f2bf(v.x);
      ls[hwl + 1][cl] = f2bf(v.y);
      ls[hwl + 2][cl] = f2bf(v.z);
      ls[hwl + 3][cl] = f2bf(v.w);
    }
  }
  __syncthreads();
  {
    int hw = tid >> 2, part = tid & 3;
    unsigned short* dst = xT + ((size_t)(n * HW + hwbase + hw)) * CIN + cbase + part * 16;
    *(uint4*)(dst + 0) = *(const uint4*)(&ls[hw][part * 16 + 0]);
    *(uint4*)(dst + 8) = *(const uint4*)(&ls[hw][part * 16 + 8]);
  }
}

// ---------------------------------------------------------------------------
// Kernel W1: main weights -> MFMA-A fragment order.
// Ag[ch][oTile(16)][lane(64)][8 bf16]: o = ot*16+(l&15), c = cc*32+(l>>4)*8+j
// ---------------------------------------------------------------------------
__global__ __launch_bounds__(256)
void wa_convert(const float* __restrict__ w, unsigned short* __restrict__ Ag) {
  int gid = blockIdx.x * 256 + threadIdx.x;  // < 72*16*64 = 73728
  int ch = gid >> 10;
  int rest = gid & 1023;
  int ot = rest >> 6, l = rest & 63;
  int o = ot * 16 + (l & 15);
  int k = ch >> 3, cc = ch & 7;
  int cbase = cc * 32 + (l >> 4) * 8;
  unsigned short r[8];
#pragma unroll
  for (int j = 0; j < 8; ++j)
    r[j] = f2bf(w[((size_t)o * CIN + cbase + j) * 9 + k]);
  uint4 pk;
  pk.x = (unsigned int)r[0] | ((unsigned int)r[1] << 16);
  pk.y = (unsigned int)r[2] | ((unsigned int)r[3] << 16);
  pk.z = (unsigned int)r[4] | ((unsigned int)r[5] << 16);
  pk.w = (unsigned int)r[6] | ((unsigned int)r[7] << 16);
  *(uint4*)(Ag + (size_t)gid * 8) = pk;
}

// ---------------------------------------------------------------------------
// Kernel W2: offset weights -> A-frag order, padded to 32 rows.
// ---------------------------------------------------------------------------
__global__ __launch_bounds__(256)
void wa2_convert(const float* __restrict__ w_off, unsigned short* __restrict__ Ag2) {
  int gid = blockIdx.x * 256 + threadIdx.x;  // < 72*2*64 = 9216
  int ch = gid >> 7;
  int rest = gid & 127;
  int ot = rest >> 6, l = rest & 63;
  int o = ot * 16 + (l & 15);
  int k = ch >> 3, cc = ch & 7;
  int cbase = cc * 32 + (l >> 4) * 8;
  unsigned short r[8];
#pragma unroll
  for (int j = 0; j < 8; ++j)
    r[j] = (o < 27) ? f2bf(w_off[((size_t)o * CIN + cbase + j) * 9 + k]) : (unsigned short)0;
  uint4 pk;
  pk.x = (unsigned int)r[0] | ((unsigned int)r[1] << 16);
  pk.y = (unsigned int)r[2] | ((unsigned int)r[3] << 16);
  pk.z = (unsigned int)r[4] | ((unsigned int)r[5] << 16);
  pk.w = (unsigned int)r[6] | ((unsigned int)r[7] << 16);
  *(uint4*)(Ag2 + (size_t)gid * 8) = pk;
}

// ---------------------------------------------------------------------------
// Kernel O: offset conv as bf16 MFMA GEMM over xT, BK=64.
// Block = 256 thr (4 waves) x 64 pixels; group g=(cc2,k) k-inner.
// Per group per thread: 2 x 16-B xT loads (integer taps); 4 MFMA/wave;
// 1 barrier/group.
// ---------------------------------------------------------------------------
__global__ __launch_bounds__(256)
void offset_gemm(const unsigned short* __restrict__ xT,
                 const unsigned short* __restrict__ Ag2,
                 const float* __restrict__ b_off,
                 float* __restrict__ py, float* __restrict__ px,
                 float* __restrict__ mk) {
  __shared__ unsigned short sB[2][4096];  // [buf][sub*2048 + tile*512 + lane*8]

  int tid = threadIdx.x;
  int wv = tid >> 6, lane = tid & 63, quad = lane >> 4, l16 = lane & 15;
  int pixBase = blockIdx.x * 64;
  int n = blockIdx.y;

  int q = tid >> 6;           // channel 16-slice within 64-group
  int pl = tid & 63;
  int tile = pl >> 4, lp = pl & 15;
  int hwp = pixBase + pl;
  int hh = hwp / W, wx = hwp % W;
  const unsigned short* xTn = xT + (size_t)n * HW * CIN;

  int pos9[9];
  bool ok9[9];
#pragma unroll
  for (int ty = 0; ty < 3; ++ty) {
#pragma unroll
    for (int tx = 0; tx < 3; ++tx) {
      int iy = hh + ty - 1, ix = wx + tx - 1;
      ok9[ty * 3 + tx] = (iy >= 0) && (iy < H) && (ix >= 0) && (ix < W);
      pos9[ty * 3 + tx] = min(max(iy, 0), H - 1) * W + min(max(ix, 0), W - 1);
    }
  }

  // store addrs (shorts): sub = q>>1, octets qq0=(q&1)*2, qq0+1
  int sSub = q >> 1, qq0 = (q & 1) * 2;
  int a0 = sSub * 2048 + tile * 512 + (qq0 * 16 + lp) * 8;
  int a1 = a0 + 128;  // (qq0+1)*16*8 - qq0*16*8

  f32x4 acc[2];
  acc[0] = (f32x4){0.f, 0.f, 0.f, 0.f};
  acc[1] = (f32x4){0.f, 0.f, 0.f, 0.f};

  uint4 d0, d1;
  auto sload = [&](int k, int cc2) {
    const unsigned short* base = xTn + (size_t)pos9[k] * CIN + cc2 * 64 + q * 16;
    d0 = *(const uint4*)(base);
    d1 = *(const uint4*)(base + 8);
    if (!ok9[k]) { d0 = (uint4){0,0,0,0}; d1 = (uint4){0,0,0,0}; }
  };

  bf16x8 afr[4], afrn[4];
  auto aload = [&](int k, int cc2, bf16x8* dst) {
    int ch = k * 8 + cc2 * 2;
#pragma unroll
    for (int s = 0; s < 2; ++s)
#pragma unroll
      for (int ot = 0; ot < 2; ++ot)
        dst[s * 2 + ot] = *(const bf16x8*)(Ag2 + ((size_t)((ch + s) * 2 + ot) * 64 + lane) * 8);
  };

  // prologue: group 0 (cc2=0, k=0)
  sload(0, 0);
  aload(0, 0, afr);
  *(uint4*)(&sB[0][a0]) = d0;
  *(uint4*)(&sB[0][a1]) = d1;
  __syncthreads();

  int kC = 0, ccC = 0;
  for (int g = 0; g < NGR; ++g) {
    int p = g & 1;
    int kN = kC + 1, ccN = ccC;
    if (kN == 9) { kN = 0; ccN = ccC + 1; }
    if (g < NGR - 1) {
      sload(kN, ccN);
      aload(kN, ccN, afrn);
    }

#pragma unroll
    for (int s = 0; s < 2; ++s) {
      bf16x8 bfr = *(const bf16x8*)(&sB[p][s * 2048 + wv * 512 + lane * 8]);
      acc[0] = __builtin_amdgcn_mfma_f32_16x16x32_bf16(afr[s * 2 + 0], bfr, acc[0], 0, 0, 0);
      acc[1] = __builtin_amdgcn_mfma_f32_16x16x32_bf16(afr[s * 2 + 1], bfr, acc[1], 0, 0, 0);
    }

    if (g < NGR - 1) {
      *(uint4*)(&sB[1 - p][a0]) = d0;
      *(uint4*)(&sB[1 - p][a1]) = d1;
      __syncthreads();
#pragma unroll
      for (int i = 0; i < 4; ++i) afr[i] = afrn[i];
      kC = kN; ccC = ccN;
    }
  }

  // Epilogue: D col = l16 (pix tile = wv), row = quad*4+r (kk)
  int pix = pixBase + wv * 16 + l16;
  int he = pix / W, we = pix % W;
#pragma unroll
  for (int ot = 0; ot < 2; ++ot) {
#pragma unroll
    for (int r = 0; r < 4; ++r) {
      int kk = ot * 16 + quad * 4 + r;
      if (kk >= 27) continue;
      float v = acc[ot][r] + b_off[kk];
      if (kk < 9) {
        py[(size_t)(n * 9 + kk) * HW + pix] = v + (float)he + (float)(kk / 3 - 1);
      } else if (kk < 18) {
        int j = kk - 9;
        px[(size_t)(n * 9 + j) * HW + pix] = v + (float)we + (float)(j % 3 - 1);
      } else {
        mk[(size_t)(n * 9 + (kk - 18)) * HW + pix] = 1.f / (1.f + expf(-v));
      }
    }
  }
}

// ---------------------------------------------------------------------------
// Kernel G: FUSED bilinear-sample + bf16 MFMA GEMM, BK=64.
// Block = 512 thr (8 waves) = 256 couts x 64 pixels; grid (144, NB).
// Group g=(cc2,k), k-inner -> consecutive groups reuse the same 64-ch row
// slices at +-1-row taps (L1-hot). Sampling: thread=(pix=lane, octet=wv),
// 4 x 16-B corner loads, blend 8 ch. 16 MFMA/wave per group; 1 barrier/group.
// Tap idx/weights register-cached per group.
// ---------------------------------------------------------------------------
__global__ __launch_bounds__(512)
void fused_gemm(const unsigned short* __restrict__ xT,
                const unsigned short* __restrict__ Ag,
                const float* __restrict__ py,
                const float* __restrict__ px,
                const float* __restrict__ mk,
                unsigned short* __restrict__ yb,
                float* __restrict__ sumArr, float* __restrict__ sqArr) {
  __shared__ int   sIdx[9][4][64];
  __shared__ float sWgt[9][4][64];
  __shared__ unsigned short sB[2][4096];  // [buf][sub*2048 + tile*512 + lane*8]

  int tid = threadIdx.x;
  int wv = tid >> 6, lane = tid & 63, quad = lane >> 4, l16 = lane & 15;
  int pixBase = blockIdx.x * 64;
  int n = blockIdx.y;
  const unsigned short* xTn = xT + (size_t)n * HW * CIN;

  // ---- prologue: corner indices + mask-folded weights, 64 pix x 9 taps
  {
    int pix0 = tid & 63;
    int k0 = tid >> 6;
#pragma unroll
    for (int rep = 0; rep < 2; ++rep) {
      int k = (rep == 0) ? k0 : 8;
      if (rep == 1 && tid >= 64) break;
      int off = (n * 9 + k) * HW + pixBase + pix0;
      float fy = py[off], fx = px[off], fm = mk[off];
      float y0f = floorf(fy), x0f = floorf(fx);
      float ly = fy - y0f, lx = fx - x0f;
      int y0 = (int)y0f, x0 = (int)x0f;
      int cy0 = min(max(y0, 0), H - 1), cy1 = min(max(y0 + 1, 0), H - 1);
      int cx0 = min(max(x0, 0), W - 1), cx1 = min(max(x0 + 1, 0), W - 1);
      float vy0 = (y0 >= 0 && y0 <= H - 1) ? 1.f : 0.f;
      float vy1 = (y0 + 1 >= 0 && y0 + 1 <= H - 1) ? 1.f : 0.f;
      float vx0 = (x0 >= 0 && x0 <= W - 1) ? 1.f : 0.f;
      float vx1 = (x0 + 1 >= 0 && x0 + 1 <= W - 1) ? 1.f : 0.f;
      sIdx[k][0][pix0] = cy0 * W + cx0;
      sIdx[k][1][pix0] = cy0 * W + cx1;
      sIdx[k][2][pix0] = cy1 * W + cx0;
      sIdx[k][3][pix0] = cy1 * W + cx1;
      sWgt[k][0][pix0] = (1.f - ly) * (1.f - lx) * fm * vy0 * vx0;
      sWgt[k][1][pix0] = (1.f - ly) * lx * fm * vy0 * vx1;
      sWgt[k][2][pix0] = ly * (1.f - lx) * fm * vy1 * vx0;
      sWgt[k][3][pix0] = ly * lx * fm * vy1 * vx1;
    }
  }
  __syncthreads();

  // sampling role: pix = lane, octet j = wv (8 channels of the 64-group)
  int sPix = lane;
  int j = wv;
  int sTile = sPix >> 4, sLp = sPix & 15;
  int sAddr = (j >> 2) * 2048 + sTile * 512 + ((j & 3) * 16 + sLp) * 8;

  f32x4 acc[2][4];
#pragma unroll
  for (int i = 0; i < 2; ++i)
#pragma unroll
    for (int pt = 0; pt < 4; ++pt) acc[i][pt] = (f32x4){0.f, 0.f, 0.f, 0.f};

  int i0, i1, i2, i3;
  float w0, w1, w2, w3;
  auto loadTap = [&](int k) {
    i0 = sIdx[k][0][sPix]; i1 = sIdx[k][1][sPix];
    i2 = sIdx[k][2][sPix]; i3 = sIdx[k][3][sPix];
    w0 = sWgt[k][0][sPix]; w1 = sWgt[k][1][sPix];
    w2 = sWgt[k][2][sPix]; w3 = sWgt[k][3][sPix];
  };

  uint4 cn[4];
  auto sload = [&](int cc2) {
    int co = cc2 * 64 + j * 8;
    cn[0] = *(const uint4*)(xTn + (size_t)i0 * CIN + co);
    cn[1] = *(const uint4*)(xTn + (size_t)i1 * CIN + co);
    cn[2] = *(const uint4*)(xTn + (size_t)i2 * CIN + co);
    cn[3] = *(const uint4*)(xTn + (size_t)i3 * CIN + co);
  };
  auto blend8 = [&]() -> uint4 {
    const unsigned int* u0 = (const unsigned int*)&cn[0];
    const unsigned int* u1 = (const unsigned int*)&cn[1];
    const unsigned int* u2 = (const unsigned int*)&cn[2];
    const unsigned int* u3 = (const unsigned int*)&cn[3];
    unsigned int r[4];
#pragma unroll
    for (int p = 0; p < 4; ++p) {
      float lo = bfLo(u0[p]) * w0;
      lo = fmaf(bfLo(u1[p]), w1, lo);
      lo = fmaf(bfLo(u2[p]), w2, lo);
      lo = fmaf(bfLo(u3[p]), w3, lo);
      float hi = bfHi(u0[p]) * w0;
      hi = fmaf(bfHi(u1[p]), w1, hi);
      hi = fmaf(bfHi(u2[p]), w2, hi);
      hi = fmaf(bfHi(u3[p]), w3, hi);
      r[p] = (unsigned int)f2bf(lo) | ((unsigned int)f2bf(hi) << 16);
    }
    return (uint4){r[0], r[1], r[2], r[3]};
  };

  bf16x8 afr[4], afrn[4];
  auto aload = [&](int k, int cc2, bf16x8* dst) {
    int ch = k * 8 + cc2 * 2;
#pragma unroll
    for (int s = 0; s < 2; ++s)
#pragma unroll
      for (int ot = 0; ot < 2; ++ot)
        dst[s * 2 + ot] = *(const bf16x8*)(Ag + ((size_t)((ch + s) * 16 + 2 * wv + ot) * 64 + lane) * 8);
  };

  // prologue: group 0
  loadTap(0);
  sload(0);
  aload(0, 0, afr);
  {
    uint4 b = blend8();
    *(uint4*)(&sB[0][sAddr]) = b;
  }
  __syncthreads();

  int kC = 0, ccC = 0;
  for (int g = 0; g < NGR; ++g) {
    int p = g & 1;
    int kN = kC + 1, ccN = ccC;
    if (kN == 9) { kN = 0; ccN = ccC + 1; }
    if (g < NGR - 1) {
      loadTap(kN);
      sload(ccN);       // corner loads in flight across MFMA phase
      aload(kN, ccN, afrn);
    }

#pragma unroll
    for (int s = 0; s < 2; ++s) {
      bf16x8 bfr[4];
#pragma unroll
      for (int pt = 0; pt < 4; ++pt)
        bfr[pt] = *(const bf16x8*)(&sB[p][s * 2048 + pt * 512 + lane * 8]);
#pragma unroll
      for (int pt = 0; pt < 4; ++pt) {
        acc[0][pt] = __builtin_amdgcn_mfma_f32_16x16x32_bf16(afr[s * 2 + 0], bfr[pt], acc[0][pt], 0, 0, 0);
        acc[1][pt] = __builtin_amdgcn_mfma_f32_16x16x32_bf16(afr[s * 2 + 1], bfr[pt], acc[1][pt], 0, 0, 0);
      }
    }

    if (g < NGR - 1) {
      uint4 b = blend8();
      *(uint4*)(&sB[1 - p][sAddr]) = b;
      __syncthreads();
#pragma unroll
      for (int i = 0; i < 4; ++i) afr[i] = afrn[i];
      kC = kN; ccC = ccN;
    }
  }

  // Epilogue: D col = l16 (pix), row = quad*4 + r (o within 16-tile)
#pragma unroll
  for (int ot = 0; ot < 2; ++ot) {
#pragma unroll
    for (int r = 0; r < 4; ++r) {
      int o = (2 * wv + ot) * 16 + quad * 4 + r;
      unsigned short* rowp = yb + (size_t)(n * COUT + o) * HW + pixBase;
      float s = 0.f, q = 0.f;
#pragma unroll
      for (int pt = 0; pt < 4; ++pt) {
        float v = acc[ot][pt][r];
        rowp[pt * 16 + l16] = f2bf(v);
        s += v;
        q = fmaf(v, v, q);
      }
#pragma unroll
      for (int m = 8; m >= 1; m >>= 1) {
        s += __shfl_xor(s, m, 64);
        q += __shfl_xor(q, m, 64);
      }
      if (l16 == 0) {
        atomicAdd(&sumArr[o], s);
        atomicAdd(&sqArr[o], q);
      }
    }
  }
}

// ---------------------------------------------------------------------------
// BN finalize + apply (bf16 y -> fp32 out)
// ---------------------------------------------------------------------------
__global__ __launch_bounds__(256)
void bn_finalize(const float* __restrict__ sumArr, const float* __restrict__ sqArr,
                 const float* __restrict__ gamma, const float* __restrict__ beta,
                 float* __restrict__ scaleArr, float* __restrict__ shiftArr) {
  int o = threadIdx.x;
  const float inv = 1.f / (float)(NB * HW);
  float mean = sumArr[o] * inv;
  float var = sqArr[o] * inv - mean * mean;
  float sc = rsqrtf(var + 1e-5f) * gamma[o];
  scaleArr[o] = sc;
  shiftArr[o] = beta[o] - mean * sc;
}

__global__ __launch_bounds__(256)
void bn_apply(const unsigned short* __restrict__ yb,
              float* __restrict__ out,
              const float* __restrict__ scaleArr,
              const float* __restrict__ shiftArr) {
  int gid = blockIdx.x * 256 + threadIdx.x;  // < NB*COUT*HW/8
  int base = gid * 8;
  int o = (base / HW) % COUT;
  float scale = scaleArr[o], shift = shiftArr[o];
  uint4 v = ((const uint4*)yb)[gid];
  float4 a, b;
  a.x = fmaxf(fmaf(bf2f((unsigned short)(v.x & 0xffff)), scale, shift), 0.f);
  a.y = fmaxf(fmaf(bf2f((unsigned short)(v.x >> 16)), scale, shift), 0.f);
  a.z = fmaxf(fmaf(bf2f((unsigned short)(v.y & 0xffff)), scale, shift), 0.f);
  a.w = fmaxf(fmaf(bf2f((unsigned short)(v.y >> 16)), scale, shift), 0.f);
  b.x = fmaxf(fmaf(bf2f((unsigned short)(v.z & 0xffff)), scale, shift), 0.f);
  b.y = fmaxf(fmaf(bf2f((unsigned short)(v.z >> 16)), scale, shift), 0.f);
  b.z = fmaxf(fmaf(bf2f((unsigned short)(v.w & 0xffff)), scale, shift), 0.f);
  b.w = fmaxf(fmaf(bf2f((unsigned short)(v.w >> 16)), scale, shift), 0.f);
  *(float4*)&out[base] = a;
  *(float4*)&out[base + 4] = b;
}

// ---------------------------------------------------------------------------
extern "C" void kernel_launch(void* const* d_in, const int* in_sizes, int n_in,
                              void* d_out, int out_size, void* d_ws, size_t ws_size,
                              hipStream_t stream) {
  const float* x     = (const float*)d_in[0];
  const float* w_off = (const float*)d_in[1];
  const float* b_off = (const float*)d_in[2];
  const float* w     = (const float*)d_in[3];
  // d_in[4] = b : cancels exactly in BN mean-subtraction
  const float* gamma = (const float*)d_in[5];
  const float* beta  = (const float*)d_in[6];
  float* out = (float*)d_out;

  float* ws = (float*)d_ws;
  float* py = ws;                          // 331776 f
  float* px = py + 331776;
  float* mk = px + 331776;
  unsigned short* Ag  = (unsigned short*)(mk + 331776);  // 589824 u16
  unsigned short* Ag2 = Ag + 589824;                     // 73728 u16
  float* sumArr   = (float*)(Ag2 + 73728);
  float* sqArr    = sumArr + 256;
  float* scaleArr = sqArr + 256;
  float* shiftArr = scaleArr + 256;
  unsigned short* yb = (unsigned short*)(shiftArr + 256);  // 9437184 u16
  unsigned short* xT = yb + 9437184;                       // 9437184 u16

  hipMemsetAsync(sumArr, 0, 512 * sizeof(float), stream);

  dim3 gT(HW / 64, CIN / 64, NB);
  xt_convert<<<gT, 256, 0, stream>>>(x, xT);

  wa_convert<<<(NCH * 16 * 64) / 256, 256, 0, stream>>>(w, Ag);
  wa2_convert<<<(NCH * 2 * 64) / 256, 256, 0, stream>>>(w_off, Ag2);

  dim3 gO(HW / 64, NB);
  offset_gemm<<<gO, 256, 0, stream>>>(xT, Ag2, b_off, py, px, mk);

  dim3 gG(HW / 64, NB);
  fused_gemm<<<gG, 512, 0, stream>>>(xT, Ag, py, px, mk, yb, sumArr, sqArr);

  bn_finalize<<<1, 256, 0, stream>>>(sumArr, sqArr, gamma, beta, scaleArr, shiftArr);
  bn_apply<<<(NB * COUT * HW / 8) / 256, 256, 0, stream>>>(yb, out, scaleArr, shiftArr);
}

// Round 8
// 281.252 us; speedup vs baseline: 3.0472x; 1.1898x over previous
//
#include <hip/hip_runtime.h>
#include <cmath>

#define H 96
#define W 96
#define HW 9216
#define CIN 256
#define COUT 256
#define NB 4
#define NCH 72   // K-chunks of 32 kc
#define NGR 36   // K-groups of 64 kc (2 chunks): g = cc2*9 + k, k-inner

typedef float f32x4 __attribute__((ext_vector_type(4)));
typedef short bf16x8 __attribute__((ext_vector_type(8)));

__device__ __forceinline__ unsigned short f2bf(float f) {
  unsigned int u = __float_as_uint(f);
  u += 0x7fff + ((u >> 16) & 1);  // round-to-nearest-even
  return (unsigned short)(u >> 16);
}
__device__ __forceinline__ float bf2f(unsigned short u) {
  return __uint_as_float(((unsigned int)u) << 16);
}
__device__ __forceinline__ float bfLo(unsigned int u) {
  return __uint_as_float(u << 16);
}
__device__ __forceinline__ float bfHi(unsigned int u) {
  return __uint_as_float(u & 0xffff0000u);
}

// ---------------------------------------------------------------------------
// Kernel T: x (N,C,HW) fp32 -> xT (N,HW,C) bf16 via LDS tile.
// ---------------------------------------------------------------------------
__global__ __launch_bounds__(256)
void xt_convert(const float* __restrict__ x, unsigned short* __restrict__ xT) {
  __shared__ unsigned short ls[64][72];
  int tid = threadIdx.x;
  int hwbase = blockIdx.x * 64;
  int cbase  = blockIdx.y * 64;
  int n      = blockIdx.z;

  {
    int cl = tid >> 2, qd = tid & 3;
    const float* src = x + ((size_t)(n * CIN + cbase + cl)) * HW + hwbase + qd * 16;
#pragma unroll
    for (int m = 0; m < 4; ++m) {
      float4 v = *(const float4*)(src + m * 4);
      int hwl = qd * 16 + m * 4;
      ls[hwl + 0][cl] = f2bf(v.x);
      ls[hwl + 1][cl] = f2bf(v.y);
      ls[hwl + 2][cl] = f2bf(v.z);
      ls[hwl + 3][cl] = f2bf(v.w);
    }
  }
  __syncthreads();
  {
    int hw = tid >> 2, part = tid & 3;
    unsigned short* dst = xT + ((size_t)(n * HW + hwbase + hw)) * CIN + cbase + part * 16;
    *(uint4*)(dst + 0) = *(const uint4*)(&ls[hw][part * 16 + 0]);
    *(uint4*)(dst + 8) = *(const uint4*)(&ls[hw][part * 16 + 8]);
  }
}

// ---------------------------------------------------------------------------
// Kernel W1: main weights -> MFMA-A fragment order.
// Ag[ch][oTile(16)][lane(64)][8 bf16]: o = ot*16+(l&15), c = cc*32+(l>>4)*8+j
// ---------------------------------------------------------------------------
__global__ __launch_bounds__(256)
void wa_convert(const float* __restrict__ w, unsigned short* __restrict__ Ag) {
  int gid = blockIdx.x * 256 + threadIdx.x;  // < 72*16*64 = 73728
  int ch = gid >> 10;
  int rest = gid & 1023;
  int ot = rest >> 6, l = rest & 63;
  int o = ot * 16 + (l & 15);
  int k = ch >> 3, cc = ch & 7;
  int cbase = cc * 32 + (l >> 4) * 8;
  unsigned short r[8];
#pragma unroll
  for (int j = 0; j < 8; ++j)
    r[j] = f2bf(w[((size_t)o * CIN + cbase + j) * 9 + k]);
  uint4 pk;
  pk.x = (unsigned int)r[0] | ((unsigned int)r[1] << 16);
  pk.y = (unsigned int)r[2] | ((unsigned int)r[3] << 16);
  pk.z = (unsigned int)r[4] | ((unsigned int)r[5] << 16);
  pk.w = (unsigned int)r[6] | ((unsigned int)r[7] << 16);
  *(uint4*)(Ag + (size_t)gid * 8) = pk;
}

// ---------------------------------------------------------------------------
// Kernel W2: offset weights -> A-frag order, padded to 32 rows.
// ---------------------------------------------------------------------------
__global__ __launch_bounds__(256)
void wa2_convert(const float* __restrict__ w_off, unsigned short* __restrict__ Ag2) {
  int gid = blockIdx.x * 256 + threadIdx.x;  // < 72*2*64 = 9216
  int ch = gid >> 7;
  int rest = gid & 127;
  int ot = rest >> 6, l = rest & 63;
  int o = ot * 16 + (l & 15);
  int k = ch >> 3, cc = ch & 7;
  int cbase = cc * 32 + (l >> 4) * 8;
  unsigned short r[8];
#pragma unroll
  for (int j = 0; j < 8; ++j)
    r[j] = (o < 27) ? f2bf(w_off[((size_t)o * CIN + cbase + j) * 9 + k]) : (unsigned short)0;
  uint4 pk;
  pk.x = (unsigned int)r[0] | ((unsigned int)r[1] << 16);
  pk.y = (unsigned int)r[2] | ((unsigned int)r[3] << 16);
  pk.z = (unsigned int)r[4] | ((unsigned int)r[5] << 16);
  pk.w = (unsigned int)r[6] | ((unsigned int)r[7] << 16);
  *(uint4*)(Ag2 + (size_t)gid * 8) = pk;
}

// ---------------------------------------------------------------------------
// Kernel O: offset conv as bf16 MFMA GEMM over xT, BK=64, coalesced staging.
// Block = 256 thr (4 waves) x 64 pixels; group g=(cc2,k) k-inner.
// Staging role: slot = {tid, tid+256}; pix = slot>>3, chunk = slot&7 ->
// 8 consecutive lanes read one row's 128 B contiguously (16 lines/inst).
// Tap positions in sPos LDS (-1 = OOB). XOR-swizzled sB store/read.
// ---------------------------------------------------------------------------
__global__ __launch_bounds__(256)
void offset_gemm(const unsigned short* __restrict__ xT,
                 const unsigned short* __restrict__ Ag2,
                 const float* __restrict__ b_off,
                 float* __restrict__ py, float* __restrict__ px,
                 float* __restrict__ mk) {
  __shared__ int sPos[9][64];
  __shared__ unsigned short sB[2][4096];

  int tid = threadIdx.x;
  int wv = tid >> 6, lane = tid & 63, quad = lane >> 4, l16 = lane & 15;
  int pixBase = blockIdx.x * 64;
  int n = blockIdx.y;
  const unsigned short* xTn = xT + (size_t)n * HW * CIN;

  // prologue: integer tap positions for 64 pixels
  if (tid < 64) {
    int hwp = pixBase + tid;
    int hh = hwp / W, wx = hwp % W;
#pragma unroll
    for (int ty = 0; ty < 3; ++ty) {
#pragma unroll
      for (int tx = 0; tx < 3; ++tx) {
        int iy = hh + ty - 1, ix = wx + tx - 1;
        bool ok = (iy >= 0) && (iy < H) && (ix >= 0) && (ix < W);
        sPos[ty * 3 + tx][tid] = ok ? (iy * W + ix) : -1;
      }
    }
  }
  __syncthreads();

  // staging slots: (pix, chunk) for slot = tid and tid+256
  int pix0 = tid >> 3, ck0 = tid & 7;
  int pix1 = 32 + (tid >> 3), ck1 = ck0;
  int a0 = (ck0 >> 2) * 2048 + (pix0 >> 4) * 512 + ((ck0 & 3) * 16 + ((pix0 & 15) ^ (ck0 & 3))) * 8;
  int a1 = (ck1 >> 2) * 2048 + (pix1 >> 4) * 512 + ((ck1 & 3) * 16 + ((pix1 & 15) ^ (ck1 & 3))) * 8;

  f32x4 acc[2];
  acc[0] = (f32x4){0.f, 0.f, 0.f, 0.f};
  acc[1] = (f32x4){0.f, 0.f, 0.f, 0.f};

  uint4 d0, d1;
  auto sload = [&](int k, int cc2) {
    int p0 = sPos[k][pix0], p1 = sPos[k][pix1];
    d0 = (uint4){0, 0, 0, 0};
    d1 = (uint4){0, 0, 0, 0};
    if (p0 >= 0) d0 = *(const uint4*)(xTn + (size_t)p0 * CIN + cc2 * 64 + ck0 * 8);
    if (p1 >= 0) d1 = *(const uint4*)(xTn + (size_t)p1 * CIN + cc2 * 64 + ck1 * 8);
  };

  bf16x8 afr[4], afrn[4];
  auto aload = [&](int k, int cc2, bf16x8* dst) {
    int ch = k * 8 + cc2 * 2;
#pragma unroll
    for (int s = 0; s < 2; ++s)
#pragma unroll
      for (int ot = 0; ot < 2; ++ot)
        dst[s * 2 + ot] = *(const bf16x8*)(Ag2 + ((size_t)((ch + s) * 2 + ot) * 64 + lane) * 8);
  };

  // prologue: group 0
  sload(0, 0);
  aload(0, 0, afr);
  *(uint4*)(&sB[0][a0]) = d0;
  *(uint4*)(&sB[0][a1]) = d1;
  __syncthreads();

  int rdAddr0 = wv * 512 + (quad * 16 + (l16 ^ quad)) * 8;

  int kC = 0, ccC = 0;
  for (int g = 0; g < NGR; ++g) {
    int p = g & 1;
    int kN = kC + 1, ccN = ccC;
    if (kN == 9) { kN = 0; ccN = ccC + 1; }
    if (g < NGR - 1) {
      sload(kN, ccN);
      aload(kN, ccN, afrn);
    }

#pragma unroll
    for (int s = 0; s < 2; ++s) {
      bf16x8 bfr = *(const bf16x8*)(&sB[p][s * 2048 + rdAddr0]);
      acc[0] = __builtin_amdgcn_mfma_f32_16x16x32_bf16(afr[s * 2 + 0], bfr, acc[0], 0, 0, 0);
      acc[1] = __builtin_amdgcn_mfma_f32_16x16x32_bf16(afr[s * 2 + 1], bfr, acc[1], 0, 0, 0);
    }

    if (g < NGR - 1) {
      *(uint4*)(&sB[1 - p][a0]) = d0;
      *(uint4*)(&sB[1 - p][a1]) = d1;
      __syncthreads();
#pragma unroll
      for (int i = 0; i < 4; ++i) afr[i] = afrn[i];
      kC = kN; ccC = ccN;
    }
  }

  // Epilogue: D col = l16 (pix tile = wv), row = quad*4+r (kk)
  int pix = pixBase + wv * 16 + l16;
  int he = pix / W, we = pix % W;
#pragma unroll
  for (int ot = 0; ot < 2; ++ot) {
#pragma unroll
    for (int r = 0; r < 4; ++r) {
      int kk = ot * 16 + quad * 4 + r;
      if (kk >= 27) continue;
      float v = acc[ot][r] + b_off[kk];
      if (kk < 9) {
        py[(size_t)(n * 9 + kk) * HW + pix] = v + (float)he + (float)(kk / 3 - 1);
      } else if (kk < 18) {
        int j = kk - 9;
        px[(size_t)(n * 9 + j) * HW + pix] = v + (float)we + (float)(j % 3 - 1);
      } else {
        mk[(size_t)(n * 9 + (kk - 18)) * HW + pix] = 1.f / (1.f + expf(-v));
      }
    }
  }
}

// ---------------------------------------------------------------------------
// Kernel G: FUSED bilinear-sample + bf16 MFMA GEMM, BK=64, coalesced gathers.
// Block = 512 thr (8 waves) = 256 couts x 64 pixels; grid (144, NB).
// Sampling role: pixS = (wv&3)*16 + (lane>>2), q = lane&3, chunk =
// (wv>>2)*4+q -> 4 consecutive lanes read one corner-row's 64-B line.
// 4 corner passes/thread; blend 8 ch in-thread; XOR-swizzled sB.
// 16 MFMA/wave/group; 1 barrier/group.
// ---------------------------------------------------------------------------
__global__ __launch_bounds__(512)
void fused_gemm(const unsigned short* __restrict__ xT,
                const unsigned short* __restrict__ Ag,
                const float* __restrict__ py,
                const float* __restrict__ px,
                const float* __restrict__ mk,
                unsigned short* __restrict__ yb,
                float* __restrict__ sumArr, float* __restrict__ sqArr) {
  __shared__ int   sIdx[9][4][64];
  __shared__ float sWgt[9][4][64];
  __shared__ unsigned short sB[2][4096];

  int tid = threadIdx.x;
  int wv = tid >> 6, lane = tid & 63, quad = lane >> 4, l16 = lane & 15;
  int pixBase = blockIdx.x * 64;
  int n = blockIdx.y;
  const unsigned short* xTn = xT + (size_t)n * HW * CIN;

  // ---- prologue: corner indices + mask-folded weights, 64 pix x 9 taps
  {
    int pix0 = tid & 63;
    int k0 = tid >> 6;
#pragma unroll
    for (int rep = 0; rep < 2; ++rep) {
      int k = (rep == 0) ? k0 : 8;
      if (rep == 1 && tid >= 64) break;
      int off = (n * 9 + k) * HW + pixBase + pix0;
      float fy = py[off], fx = px[off], fm = mk[off];
      float y0f = floorf(fy), x0f = floorf(fx);
      float ly = fy - y0f, lx = fx - x0f;
      int y0 = (int)y0f, x0 = (int)x0f;
      int cy0 = min(max(y0, 0), H - 1), cy1 = min(max(y0 + 1, 0), H - 1);
      int cx0 = min(max(x0, 0), W - 1), cx1 = min(max(x0 + 1, 0), W - 1);
      float vy0 = (y0 >= 0 && y0 <= H - 1) ? 1.f : 0.f;
      float vy1 = (y0 + 1 >= 0 && y0 + 1 <= H - 1) ? 1.f : 0.f;
      float vx0 = (x0 >= 0 && x0 <= W - 1) ? 1.f : 0.f;
      float vx1 = (x0 + 1 >= 0 && x0 + 1 <= W - 1) ? 1.f : 0.f;
      sIdx[k][0][pix0] = cy0 * W + cx0;
      sIdx[k][1][pix0] = cy0 * W + cx1;
      sIdx[k][2][pix0] = cy1 * W + cx0;
      sIdx[k][3][pix0] = cy1 * W + cx1;
      sWgt[k][0][pix0] = (1.f - ly) * (1.f - lx) * fm * vy0 * vx0;
      sWgt[k][1][pix0] = (1.f - ly) * lx * fm * vy0 * vx1;
      sWgt[k][2][pix0] = ly * (1.f - lx) * fm * vy1 * vx0;
      sWgt[k][3][pix0] = ly * lx * fm * vy1 * vx1;
    }
  }
  __syncthreads();

  // sampling role (coalesced): 4 consecutive lanes = 1 corner-row line
  int pixS  = ((wv & 3) << 4) | (lane >> 2);  // 0..63
  int qS    = lane & 3;
  int chunk = ((wv >> 2) << 2) | qS;          // 0..7 (8-ch chunk in 64-group)
  int co    = chunk * 8;                      // channel offset within group
  int sAddr = (chunk >> 2) * 2048 + (wv & 3) * 512 +
              ((qS << 4) | ((lane >> 2) & 15) ^ (qS & 0)) * 8;  // placeholder, fixed below
  sAddr = (chunk >> 2) * 2048 + (wv & 3) * 512 + (qS * 16 + ((lane >> 2) ^ qS)) * 8;

  f32x4 acc[2][4];
#pragma unroll
  for (int i = 0; i < 2; ++i)
#pragma unroll
    for (int pt = 0; pt < 4; ++pt) acc[i][pt] = (f32x4){0.f, 0.f, 0.f, 0.f};

  int i0, i1, i2, i3;
  float w0, w1, w2, w3;
  auto loadTap = [&](int k) {
    i0 = sIdx[k][0][pixS]; i1 = sIdx[k][1][pixS];
    i2 = sIdx[k][2][pixS]; i3 = sIdx[k][3][pixS];
    w0 = sWgt[k][0][pixS]; w1 = sWgt[k][1][pixS];
    w2 = sWgt[k][2][pixS]; w3 = sWgt[k][3][pixS];
  };

  uint4 cn[4];
  auto sload = [&](int cc2) {
    int coff = cc2 * 64 + co;
    cn[0] = *(const uint4*)(xTn + (size_t)i0 * CIN + coff);
    cn[1] = *(const uint4*)(xTn + (size_t)i1 * CIN + coff);
    cn[2] = *(const uint4*)(xTn + (size_t)i2 * CIN + coff);
    cn[3] = *(const uint4*)(xTn + (size_t)i3 * CIN + coff);
  };
  auto blend8 = [&]() -> uint4 {
    const unsigned int* u0 = (const unsigned int*)&cn[0];
    const unsigned int* u1 = (const unsigned int*)&cn[1];
    const unsigned int* u2 = (const unsigned int*)&cn[2];
    const unsigned int* u3 = (const unsigned int*)&cn[3];
    unsigned int r[4];
#pragma unroll
    for (int p = 0; p < 4; ++p) {
      float lo = bfLo(u0[p]) * w0;
      lo = fmaf(bfLo(u1[p]), w1, lo);
      lo = fmaf(bfLo(u2[p]), w2, lo);
      lo = fmaf(bfLo(u3[p]), w3, lo);
      float hi = bfHi(u0[p]) * w0;
      hi = fmaf(bfHi(u1[p]), w1, hi);
      hi = fmaf(bfHi(u2[p]), w2, hi);
      hi = fmaf(bfHi(u3[p]), w3, hi);
      r[p] = (unsigned int)f2bf(lo) | ((unsigned int)f2bf(hi) << 16);
    }
    return (uint4){r[0], r[1], r[2], r[3]};
  };

  bf16x8 afr[4], afrn[4];
  auto aload = [&](int k, int cc2, bf16x8* dst) {
    int ch = k * 8 + cc2 * 2;
#pragma unroll
    for (int s = 0; s < 2; ++s)
#pragma unroll
      for (int ot = 0; ot < 2; ++ot)
        dst[s * 2 + ot] = *(const bf16x8*)(Ag + ((size_t)((ch + s) * 16 + 2 * wv + ot) * 64 + lane) * 8);
  };

  // prologue: group 0
  loadTap(0);
  sload(0);
  aload(0, 0, afr);
  {
    uint4 b = blend8();
    *(uint4*)(&sB[0][sAddr]) = b;
  }
  __syncthreads();

  int rdBase = (quad * 16 + (l16 ^ quad)) * 8;

  int kC = 0, ccC = 0;
  for (int g = 0; g < NGR; ++g) {
    int p = g & 1;
    int kN = kC + 1, ccN = ccC;
    if (kN == 9) { kN = 0; ccN = ccC + 1; }
    if (g < NGR - 1) {
      loadTap(kN);
      sload(ccN);       // corner loads in flight across MFMA phase
      aload(kN, ccN, afrn);
    }

#pragma unroll
    for (int s = 0; s < 2; ++s) {
      bf16x8 bfr[4];
#pragma unroll
      for (int pt = 0; pt < 4; ++pt)
        bfr[pt] = *(const bf16x8*)(&sB[p][s * 2048 + pt * 512 + rdBase]);
#pragma unroll
      for (int pt = 0; pt < 4; ++pt) {
        acc[0][pt] = __builtin_amdgcn_mfma_f32_16x16x32_bf16(afr[s * 2 + 0], bfr[pt], acc[0][pt], 0, 0, 0);
        acc[1][pt] = __builtin_amdgcn_mfma_f32_16x16x32_bf16(afr[s * 2 + 1], bfr[pt], acc[1][pt], 0, 0, 0);
      }
    }

    if (g < NGR - 1) {
      uint4 b = blend8();
      *(uint4*)(&sB[1 - p][sAddr]) = b;
      __syncthreads();
#pragma unroll
      for (int i = 0; i < 4; ++i) afr[i] = afrn[i];
      kC = kN; ccC = ccN;
    }
  }

  // Epilogue: D col = l16 (pix), row = quad*4 + r (o within 16-tile)
#pragma unroll
  for (int ot = 0; ot < 2; ++ot) {
#pragma unroll
    for (int r = 0; r < 4; ++r) {
      int o = (2 * wv + ot) * 16 + quad * 4 + r;
      unsigned short* rowp = yb + (size_t)(n * COUT + o) * HW + pixBase;
      float s = 0.f, q = 0.f;
#pragma unroll
      for (int pt = 0; pt < 4; ++pt) {
        float v = acc[ot][pt][r];
        rowp[pt * 16 + l16] = f2bf(v);
        s += v;
        q = fmaf(v, v, q);
      }
#pragma unroll
      for (int m = 8; m >= 1; m >>= 1) {
        s += __shfl_xor(s, m, 64);
        q += __shfl_xor(q, m, 64);
      }
      if (l16 == 0) {
        atomicAdd(&sumArr[o], s);
        atomicAdd(&sqArr[o], q);
      }
    }
  }
}

// ---------------------------------------------------------------------------
// BN finalize + apply (bf16 y -> fp32 out)
// ---------------------------------------------------------------------------
__global__ __launch_bounds__(256)
void bn_finalize(const float* __restrict__ sumArr, const float* __restrict__ sqArr,
                 const float* __restrict__ gamma, const float* __restrict__ beta,
                 float* __restrict__ scaleArr, float* __restrict__ shiftArr) {
  int o = threadIdx.x;
  const float inv = 1.f / (float)(NB * HW);
  float mean = sumArr[o] * inv;
  float var = sqArr[o] * inv - mean * mean;
  float sc = rsqrtf(var + 1e-5f) * gamma[o];
  scaleArr[o] = sc;
  shiftArr[o] = beta[o] - mean * sc;
}

__global__ __launch_bounds__(256)
void bn_apply(const unsigned short* __restrict__ yb,
              float* __restrict__ out,
              const float* __restrict__ scaleArr,
              const float* __restrict__ shiftArr) {
  int gid = blockIdx.x * 256 + threadIdx.x;  // < NB*COUT*HW/8
  int base = gid * 8;
  int o = (base / HW) % COUT;
  float scale = scaleArr[o], shift = shiftArr[o];
  uint4 v = ((const uint4*)yb)[gid];
  float4 a, b;
  a.x = fmaxf(fmaf(bf2f((unsigned short)(v.x & 0xffff)), scale, shift), 0.f);
  a.y = fmaxf(fmaf(bf2f((unsigned short)(v.x >> 16)), scale, shift), 0.f);
  a.z = fmaxf(fmaf(bf2f((unsigned short)(v.y & 0xffff)), scale, shift), 0.f);
  a.w = fmaxf(fmaf(bf2f((unsigned short)(v.y >> 16)), scale, shift), 0.f);
  b.x = fmaxf(fmaf(bf2f((unsigned short)(v.z & 0xffff)), scale, shift), 0.f);
  b.y = fmaxf(fmaf(bf2f((unsigned short)(v.z >> 16)), scale, shift), 0.f);
  b.z = fmaxf(fmaf(bf2f((unsigned short)(v.w & 0xffff)), scale, shift), 0.f);
  b.w = fmaxf(fmaf(bf2f((unsigned short)(v.w >> 16)), scale, shift), 0.f);
  *(float4*)&out[base] = a;
  *(float4*)&out[base + 4] = b;
}

// ---------------------------------------------------------------------------
extern "C" void kernel_launch(void* const* d_in, const int* in_sizes, int n_in,
                              void* d_out, int out_size, void* d_ws, size_t ws_size,
                              hipStream_t stream) {
  const float* x     = (const float*)d_in[0];
  const float* w_off = (const float*)d_in[1];
  const float* b_off = (const float*)d_in[2];
  const float* w     = (const float*)d_in[3];
  // d_in[4] = b : cancels exactly in BN mean-subtraction
  const float* gamma = (const float*)d_in[5];
  const float* beta  = (const float*)d_in[6];
  float* out = (float*)d_out;

  float* ws = (float*)d_ws;
  float* py = ws;                          // 331776 f
  float* px = py + 331776;
  float* mk = px + 331776;
  unsigned short* Ag  = (unsigned short*)(mk + 331776);  // 589824 u16
  unsigned short* Ag2 = Ag + 589824;                     // 73728 u16
  float* sumArr   = (float*)(Ag2 + 73728);
  float* sqArr    = sumArr + 256;
  float* scaleArr = sqArr + 256;
  float* shiftArr = scaleArr + 256;
  unsigned short* yb = (unsigned short*)(shiftArr + 256);  // 9437184 u16
  unsigned short* xT = yb + 9437184;                       // 9437184 u16

  hipMemsetAsync(sumArr, 0, 512 * sizeof(float), stream);

  dim3 gT(HW / 64, CIN / 64, NB);
  xt_convert<<<gT, 256, 0, stream>>>(x, xT);

  wa_convert<<<(NCH * 16 * 64) / 256, 256, 0, stream>>>(w, Ag);
  wa2_convert<<<(NCH * 2 * 64) / 256, 256, 0, stream>>>(w_off, Ag2);

  dim3 gO(HW / 64, NB);
  offset_gemm<<<gO, 256, 0, stream>>>(xT, Ag2, b_off, py, px, mk);

  dim3 gG(HW / 64, NB);
  fused_gemm<<<gG, 512, 0, stream>>>(xT, Ag, py, px, mk, yb, sumArr, sqArr);

  bn_finalize<<<1, 256, 0, stream>>>(sumArr, sqArr, gamma, beta, scaleArr, shiftArr);
  bn_apply<<<(NB * COUT * HW / 8) / 256, 256, 0, stream>>>(yb, out, scaleArr, shiftArr);
}